// Round 3
// baseline (166.263 us; speedup 1.0000x reference)
//
#include <hip/hip_runtime.h>
#include <hip/hip_bf16.h>
#include <stdint.h>

#define T_SEQ 4096

typedef float  f32x4   __attribute__((ext_vector_type(4)));
typedef float  f32x16  __attribute__((ext_vector_type(16)));
typedef short  bf16x8  __attribute__((ext_vector_type(8)));
typedef unsigned int u32x4 __attribute__((ext_vector_type(4)));

typedef const __attribute__((address_space(1))) uint32_t* gptr_t;
typedef __attribute__((address_space(3))) uint32_t* lptr_t;

__device__ __forceinline__ uint32_t f2bf1(float f) {
    uint32_t u = __float_as_uint(f);
    return (u + 0x7fffu + ((u >> 16) & 1u)) >> 16;   // RNE f32->bf16
}
__device__ __forceinline__ short f2bfs(float f) { return (short)f2bf1(f); }
__device__ __forceinline__ uint32_t cvtpk(float lo, float hi) {
    uint32_t r;
    asm("v_cvt_pk_bf16_f32 %0, %1, %2" : "=v"(r) : "v"(lo), "v"(hi));
    return r;
}

// ---------------------------------------------------------------------------
// Kernel 1: Q,K projections. Q pre-scaled by 0.125*log2(e) (softmax uses 2^x).
// Layout: [bh=b*2+h][t][64] bf16.
// ---------------------------------------------------------------------------
__global__ __launch_bounds__(256) void qk_proj(
    const float* __restrict__ x,
    const float* __restrict__ Wq1, const float* __restrict__ Wk1,
    const float* __restrict__ Wq2, const float* __restrict__ Wk2,
    short* __restrict__ Q, short* __restrict__ K)
{
    int idx = blockIdx.x * 256 + threadIdx.x;
    int d = idx & 63;
    int t = (idx >> 6) & (T_SEQ - 1);
    int b = idx >> 18;
    const float* xp = x + (size_t)(b * T_SEQ + t) * 6;
    float x0 = xp[0], x1 = xp[1], x2 = xp[2];
    float x3 = xp[3], x4 = xp[4], x5 = xp[5];
    const float QS = 0.125f * 1.44269504088896340736f;
    float q1 = (x0 * Wq1[d] + x1 * Wq1[64 + d] + x2 * Wq1[128 + d]) * QS;
    float k1 =  x0 * Wk1[d] + x1 * Wk1[64 + d] + x2 * Wk1[128 + d];
    float q2 = (x3 * Wq2[d] + x4 * Wq2[64 + d] + x5 * Wq2[128 + d]) * QS;
    float k2 =  x3 * Wk2[d] + x4 * Wk2[64 + d] + x5 * Wk2[128 + d];
    size_t base1 = ((size_t)(b * 2 + 0) * T_SEQ + t) * 64 + d;
    size_t base2 = ((size_t)(b * 2 + 1) * T_SEQ + t) * 64 + d;
    Q[base1] = f2bfs(q1);  Q[base2] = f2bfs(q2);
    K[base1] = f2bfs(k1);  K[base2] = f2bfs(k2);
}

// ---------------------------------------------------------------------------
// Kernel 2: V projection written TRANSPOSED: Vt[bh][d][t] bf16.
// ---------------------------------------------------------------------------
__global__ __launch_bounds__(256) void v_proj_t(
    const float* __restrict__ x,
    const float* __restrict__ Wv1, const float* __restrict__ Wv2,
    short* __restrict__ Vt)
{
    int bh = blockIdx.x >> 6;
    int tt = blockIdx.x & 63;
    int head = bh & 1, b = bh >> 1;
    int t  = tt * 64 + (threadIdx.x & 63);
    int dg = threadIdx.x >> 6;
    const float* Wv = head ? Wv2 : Wv1;
    const float* xp = x + (size_t)(b * T_SEQ + t) * 6 + head * 3;
    float x0 = xp[0], x1 = xp[1], x2 = xp[2];
    size_t base = (size_t)bh * 64 * T_SEQ + t;
    #pragma unroll
    for (int k = 0; k < 16; ++k) {
        int d = dg * 16 + k;
        float v = x0 * Wv[d] + x1 * Wv[64 + d] + x2 * Wv[128 + d];
        Vt[base + (size_t)d * T_SEQ] = f2bfs(v);
    }
}

// ---------------------------------------------------------------------------
// Kernel 3: causal flash attention, FOLDED, barrier-free, PHASE-PIPELINED.
//   R3: same per-wave-owned pipeline as R2 (2 waves, wave W owns kv-half,
//   K staged per-wave via global_load_lds dbuf, V reg-prefetched depth-2,
//   counted vmcnt, no in-loop barriers), but the body is restructured into
//   PHASES so the two fold tiles pipeline inside the wave:
//       QK_B -> QK_A -> SM_B -> SM_A -> PV_B -> PV_A
//   In-order issue overlaps A's MFMAs with B's QK latency, B's softmax
//   (VALU/trans) with the MFMA pipe, etc. Chain paid once per PAIR.
//   Plus: kf fragments are ds_read ONE BODY AHEAD at body end, gated by
//   `s_waitcnt vmcnt(4)` (K staged before V, so oldest-4 = next K stage).
//   Removes ds_read latency + the top-of-body wait from the critical path.
//   Never vmcnt(0) in the loop. MASK RULE: mask iff kv0+32W+31 > t0X.
// ---------------------------------------------------------------------------
__global__ __launch_bounds__(128, 2) void attn(
    const short* __restrict__ Q, const short* __restrict__ K,
    const short* __restrict__ Vt, float* __restrict__ Hf)
{
    __shared__ __align__(16) char smem[19456];  // 16KB K dbuf; combine reuses

    int id = blockIdx.x;
    int xcd = id & 7, j = id >> 3;       // j 0..127
    int bh = xcd * 2 + (j & 1);          // 2 bh per XCD (L2 locality)
    int i  = j >> 1;                     // fold index 0..63
    int tid = threadIdx.x;
    int W = tid >> 6;                    // wave = kv-half
    int lane = tid & 63;
    int ql = lane & 31, h = lane >> 5;
    int t0A = 32 * i, t0B = 32 * (127 - i);
    int qA = t0A + ql, qB = t0B + ql;
    int sweep = ((127 - i) >> 1) + 1;    // chunks (tile B extent), 33..64

    size_t kvbase = (size_t)bh * (T_SEQ * 64);

    // Q fragments for both tiles (B-operand): lane holds Q[q][ks*16+h*8+j]
    bf16x8 qfA[4], qfB[4];
    #pragma unroll
    for (int ks = 0; ks < 4; ++ks) {
        qfA[ks] = *(const bf16x8*)(Q + kvbase + (size_t)qA * 64 + ks * 16 + h * 8);
        qfB[ks] = *(const bf16x8*)(Q + kvbase + (size_t)qB * 64 + ks * 16 + h * 8);
    }

    // Per-wave K staging: 64 lanes cover 8 rows x 128B per instr, 4 instrs =
    // this wave's 32 kv rows. Pre-swizzled source column, LDS dest linear.
    int r8 = lane >> 3;                  // 0..7 (row within 8-row group)
    int scol = ((lane & 7) ^ r8) * 8;
    const short* ksrc0 = K + kvbase + scol;

    // V direct-from-global row pointers (d = ql and d = 32+ql)
    const short* vrow0 = Vt + kvbase + (size_t)ql * T_SEQ;
    const short* vrow1 = vrow0 + (size_t)32 * T_SEQ;

    f32x16 accA0, accA1, accB0, accB1;
    #pragma unroll
    for (int r = 0; r < 16; ++r) { accA0[r]=0.f; accA1[r]=0.f; accB0[r]=0.f; accB1[r]=0.f; }
    float lA = 0.f, lB = 0.f;
    int swz = (ql & 7) << 4;

    bf16x8 kf0, kf1, kf2, kf3;           // persistent, prefetched 1 body ahead

#define STAGEK(bsel, kvv)                                                       \
    {                                                                           \
        char* kb = smem + (bsel) * 8192 + W * 4096;                             \
        _Pragma("unroll")                                                       \
        for (int z = 0; z < 4; ++z) {                                           \
            int srow = (kvv) + 32 * W + z * 8 + r8;                             \
            srow = srow > (T_SEQ - 1) ? (T_SEQ - 1) : srow;                     \
            __builtin_amdgcn_global_load_lds(                                   \
                (gptr_t)(ksrc0 + (size_t)srow * 64),                            \
                (lptr_t)(kb + z * 1024), 16, 0, 0);                             \
        }                                                                       \
    }

#define VISSUE(v0, v1, v2, v3, kvv)                                             \
    {                                                                           \
        int kvw = (kvv) + 32 * W + 8 * h;                                       \
        int kvc = kvw > (T_SEQ - 24) ? (T_SEQ - 24) : kvw;                      \
        v0 = *(const bf16x8*)(vrow0 + kvc);                                     \
        v1 = *(const bf16x8*)(vrow0 + kvc + 16);                                \
        v2 = *(const bf16x8*)(vrow1 + kvc);                                     \
        v3 = *(const bf16x8*)(vrow1 + kvc + 16);                                \
    }

#define KFREAD(bsel)                                                            \
    {                                                                           \
        const char* krow = smem + (bsel) * 8192 + W * 4096 + ql * 128;          \
        kf0 = *(const bf16x8*)(krow + ((0 * 32 + h * 16) ^ swz));               \
        kf1 = *(const bf16x8*)(krow + ((1 * 32 + h * 16) ^ swz));               \
        kf2 = *(const bf16x8*)(krow + ((2 * 32 + h * 16) ^ swz));               \
        kf3 = *(const bf16x8*)(krow + ((3 * 32 + h * 16) ^ swz));               \
    }

#define QK4(Sv, qfX)                                                            \
    {                                                                           \
        _Pragma("unroll") for (int r = 0; r < 16; ++r) Sv[r] = 0.f;             \
        Sv = __builtin_amdgcn_mfma_f32_32x32x16_bf16(kf0, qfX[0], Sv, 0, 0, 0); \
        Sv = __builtin_amdgcn_mfma_f32_32x32x16_bf16(kf1, qfX[1], Sv, 0, 0, 0); \
        Sv = __builtin_amdgcn_mfma_f32_32x32x16_bf16(kf2, qfX[2], Sv, 0, 0, 0); \
        Sv = __builtin_amdgcn_mfma_f32_32x32x16_bf16(kf3, qfX[3], Sv, 0, 0, 0); \
    }

#define SM(Sv, qX, lX, pf0, pf1)                                                \
    {                                                                           \
        bool needmask = (kv0 + 32 * W + 31 > (qX) - ql);  /* max_kv > t0X */    \
        uint32_t pw[8];                                                         \
        float l0 = 0.f, l1 = 0.f;                                               \
        _Pragma("unroll") for (int e = 0; e < 8; ++e) {                         \
            float p0 = __builtin_amdgcn_exp2f(Sv[2 * e]);                       \
            float p1 = __builtin_amdgcn_exp2f(Sv[2 * e + 1]);                   \
            if (needmask) {                                                     \
                int kv = kv0 + 32 * W + 4 * h + 2 * (e & 1) + 8 * (e >> 1);     \
                p0 = (kv     <= (qX)) ? p0 : 0.f;                               \
                p1 = (kv + 1 <= (qX)) ? p1 : 0.f;                               \
            }                                                                   \
            l0 += p0; l1 += p1;                                                 \
            pw[e] = cvtpk(p0, p1);                                              \
        }                                                                       \
        lX += l0 + l1;                                                          \
        {                                                                       \
            uint32_t a0 = pw[0], b0 = pw[2], a1 = pw[1], b1 = pw[3];            \
            asm("v_permlane32_swap_b32 %0, %1" : "+v"(a0), "+v"(b0));           \
            asm("v_permlane32_swap_b32 %0, %1" : "+v"(a1), "+v"(b1));           \
            u32x4 fr = {a0, a1, b0, b1};                                        \
            pf0 = __builtin_bit_cast(bf16x8, fr);                               \
            uint32_t c0 = pw[4], d0 = pw[6], c1 = pw[5], d1 = pw[7];            \
            asm("v_permlane32_swap_b32 %0, %1" : "+v"(c0), "+v"(d0));           \
            asm("v_permlane32_swap_b32 %0, %1" : "+v"(c1), "+v"(d1));           \
            u32x4 fr1 = {c0, c1, d0, d1};                                       \
            pf1 = __builtin_bit_cast(bf16x8, fr1);                              \
        }                                                                       \
    }

#define PV4(a0, a1, pf0, pf1, v0, v1, v2, v3)                                   \
    {                                                                           \
        a0 = __builtin_amdgcn_mfma_f32_32x32x16_bf16(v0, pf0, a0, 0, 0, 0);     \
        a0 = __builtin_amdgcn_mfma_f32_32x32x16_bf16(v1, pf1, a0, 0, 0, 0);     \
        a1 = __builtin_amdgcn_mfma_f32_32x32x16_bf16(v2, pf0, a1, 0, 0, 0);     \
        a1 = __builtin_amdgcn_mfma_f32_32x32x16_bf16(v3, pf1, a1, 0, 0, 0);     \
    }

#define BODY(cc, v0, v1, v2, v3)                                                \
    {                                                                           \
        const int kv0 = (cc) * 64;                                              \
        bool actA = (kv0 + 32 * W <= t0A + 31);                                 \
        bool actB = (kv0 + 32 * W <= t0B + 31);                                 \
        f32x16 SvA, SvB;                                                        \
        bf16x8 pfA0, pfA1, pfB0, pfB1;                                          \
        __builtin_amdgcn_s_setprio(1);                                          \
        if (actB) QK4(SvB, qfB)                                                 \
        if (actA) QK4(SvA, qfA)                                                 \
        if (actB) SM(SvB, qB, lB, pfB0, pfB1)                                   \
        if (actA) SM(SvA, qA, lA, pfA0, pfA1)                                   \
        if (actB) PV4(accB0, accB1, pfB0, pfB1, v0, v1, v2, v3)                 \
        if (actA) PV4(accA0, accA1, pfA0, pfA1, v0, v1, v2, v3)                 \
        __builtin_amdgcn_s_setprio(0);                                          \
        asm volatile("s_waitcnt vmcnt(4)" ::: "memory");                        \
        KFREAD(((cc) + 1) & 1)                                                  \
        STAGEK((cc) & 1, kv0 + 128);                                            \
        VISSUE(v0, v1, v2, v3, kv0 + 128);                                      \
    }

    // Prologue: K chunk0 -> buf0, V chunk0 -> regs, K chunk1 -> buf1,
    // V chunk1 -> regs (16 outstanding); retire K0 (oldest 4) and read kf0.
    bf16x8 vfA0, vfA1, vfA2, vfA3, vfB0, vfB1, vfB2, vfB3;
    STAGEK(0, 0);
    VISSUE(vfA0, vfA1, vfA2, vfA3, 0);
    STAGEK(1, 64);
    VISSUE(vfB0, vfB1, vfB2, vfB3, 64);
    asm volatile("s_waitcnt vmcnt(12)" ::: "memory");
    KFREAD(0)

    int c = 0;
    for (;;) {
        BODY(c, vfA0, vfA1, vfA2, vfA3);
        if (++c >= sweep) break;
        BODY(c, vfB0, vfB1, vfB2, vfB3);
        if (++c >= sweep) break;
    }
#undef BODY
#undef PV4
#undef SM
#undef QK4
#undef KFREAD
#undef VISSUE
#undef STAGEK

    // ---- cross-wave combine: wave0 finalizes tile A, wave1 tile B ----
    // The barrier's implicit vmcnt(0)+lgkmcnt(0) drain covers the in-flight
    // ghost prefetches before smem is reused as the combine buffer.
    __syncthreads();
    lA += __shfl_xor(lA, 32);
    lB += __shfl_xor(lB, 32);
    float* cbuf = (float*)smem;          // [2 tiles][64 lanes][36 f32]
    float* lbuf = cbuf + 4608;           // [2][64]
    if (W == 0) {                        // write MY tile-B partial to slot 1
        float* pb = cbuf + 2304 + lane * 36;
        #pragma unroll
        for (int g2 = 0; g2 < 4; ++g2) {
            *(f32x4*)(pb + g2 * 4)      = f32x4{accB0[g2*4+0], accB0[g2*4+1], accB0[g2*4+2], accB0[g2*4+3]};
            *(f32x4*)(pb + 16 + g2 * 4) = f32x4{accB1[g2*4+0], accB1[g2*4+1], accB1[g2*4+2], accB1[g2*4+3]};
        }
        lbuf[64 + lane] = lB;
    } else {                             // write MY tile-A partial to slot 0
        float* pb = cbuf + lane * 36;
        #pragma unroll
        for (int g2 = 0; g2 < 4; ++g2) {
            *(f32x4*)(pb + g2 * 4)      = f32x4{accA0[g2*4+0], accA0[g2*4+1], accA0[g2*4+2], accA0[g2*4+3]};
            *(f32x4*)(pb + 16 + g2 * 4) = f32x4{accA1[g2*4+0], accA1[g2*4+1], accA1[g2*4+2], accA1[g2*4+3]};
        }
        lbuf[lane] = lA;
    }
    __syncthreads();
    {
        float* pb = cbuf + W * 2304 + lane * 36;
        float lf = (W ? lB : lA) + lbuf[W * 64 + lane];
        float rl = 1.0f / lf;
        int t0 = W ? t0B : t0A;
        f32x16 a0 = W ? accB0 : accA0;
        f32x16 a1 = W ? accB1 : accA1;
        int head = bh & 1, b = bh >> 1;
        float* hp = Hf + ((size_t)(b * T_SEQ) + t0 + ql) * 128 + head * 64 + 4 * h;
        #pragma unroll
        for (int g2 = 0; g2 < 4; ++g2) {
            f32x4 o0 = *(f32x4*)(pb + g2 * 4);
            f32x4 o1 = *(f32x4*)(pb + 16 + g2 * 4);
            f32x4 s0 = { (a0[g2*4+0]+o0[0])*rl, (a0[g2*4+1]+o0[1])*rl,
                         (a0[g2*4+2]+o0[2])*rl, (a0[g2*4+3]+o0[3])*rl };
            *(f32x4*)(hp + 8 * g2) = s0;               // d = 8*g2+4h+0..3
            f32x4 s1 = { (a1[g2*4+0]+o1[0])*rl, (a1[g2*4+1]+o1[1])*rl,
                         (a1[g2*4+2]+o1[2])*rl, (a1[g2*4+3]+o1[3])*rl };
            *(f32x4*)(hp + 32 + 8 * g2) = s1;          // d = 32+8*g2+4h+0..3
        }
    }
}

// ---------------------------------------------------------------------------
// Kernel 4a: one-shot Wout -> Wt bf16, transposed + xor-swizzled for LDS.
// ---------------------------------------------------------------------------
__global__ __launch_bounds__(256) void prep_wt(
    const float* __restrict__ Wout, short* __restrict__ Wt)
{
    int tid = blockIdx.x * 256 + threadIdx.x;   // 16384
    int j = tid >> 7, k = tid & 127;
    float v = Wout[k * 128 + j];
    int slot = k >> 3;
    Wt[j * 128 + (((slot ^ (j & 7)) << 3) | (k & 7))] = f2bfs(v);
}

// ---------------------------------------------------------------------------
// Kernel 4b: out = H(32768x128 f32, in d_out) @ Wout -> f32 (in place).
// Row-block-diagonal: each wave reads only its own 16 rows before writing.
// ---------------------------------------------------------------------------
__global__ __launch_bounds__(256) void out_proj(
    const float* Hf, const short* __restrict__ Wt, float* out)
{
    __shared__ __align__(16) char lws[32768];
    int tid = threadIdx.x;
    int w = tid >> 6, lane = tid & 63, c = lane & 15, g = lane >> 4;
    int cs = c & 7;
    #pragma unroll
    for (int z = 0; z < 8; ++z)
        __builtin_amdgcn_global_load_lds((gptr_t)(Wt + z * 2048 + w * 512 + lane * 8),
                                         (lptr_t)(lws + z * 4096 + w * 1024), 16, 0, 0);
    __syncthreads();

    int row0 = blockIdx.x * 64 + w * 16;
    bf16x8 af[4];
    const float* hp = Hf + (size_t)(row0 + c) * 128 + g * 8;
    #pragma unroll
    for (int kc = 0; kc < 4; ++kc) {
        f32x4 x0 = *(const f32x4*)(hp + kc * 32);
        f32x4 x1 = *(const f32x4*)(hp + kc * 32 + 4);
        u32x4 wv = { cvtpk(x0[0], x0[1]), cvtpk(x0[2], x0[3]),
                     cvtpk(x1[0], x1[1]), cvtpk(x1[2], x1[3]) };
        af[kc] = __builtin_bit_cast(bf16x8, wv);
    }
    #pragma unroll
    for (int jt = 0; jt < 8; ++jt) {
        f32x4 accum = {0.f, 0.f, 0.f, 0.f};
        #pragma unroll
        for (int kc = 0; kc < 4; ++kc) {
            int row = jt * 16 + c;
            bf16x8 bfr = *(const bf16x8*)(lws + row * 256 + (((kc * 4 + g) ^ cs) << 4));
            accum = __builtin_amdgcn_mfma_f32_16x16x32_bf16(af[kc], bfr, accum, 0, 0, 0);
        }
        #pragma unroll
        for (int r = 0; r < 4; ++r)
            out[(size_t)(row0 + g * 4 + r) * 128 + jt * 16 + c] = accum[r];
    }
}

// ---------------------------------------------------------------------------
extern "C" void kernel_launch(void* const* d_in, const int* in_sizes, int n_in,
                              void* d_out, int out_size, void* d_ws, size_t ws_size,
                              hipStream_t stream)
{
    (void)in_sizes; (void)n_in; (void)out_size; (void)ws_size;
    const float* x    = (const float*)d_in[0];
    const float* Wq1  = (const float*)d_in[1];
    const float* Wk1  = (const float*)d_in[2];
    const float* Wv1  = (const float*)d_in[3];
    const float* Wq2  = (const float*)d_in[4];
    const float* Wk2  = (const float*)d_in[5];
    const float* Wv2  = (const float*)d_in[6];
    const float* Wout = (const float*)d_in[7];
    float* out = (float*)d_out;

    char* ws = (char*)d_ws;
    short* Q  = (short*)(ws);                               // 8 MiB (dead after attn)
    short* K  = (short*)(ws + (size_t)8  * 1024 * 1024);    // 8 MiB
    short* Vt = (short*)(ws + (size_t)16 * 1024 * 1024);    // 8 MiB
    short* Wt = Q;                                          // reuse Q region
    float* Hf = out;                                        // f32 H lives in d_out

    qk_proj <<<8192, 256, 0, stream>>>(x, Wq1, Wk1, Wq2, Wk2, Q, K);
    v_proj_t<<<1024, 256, 0, stream>>>(x, Wv1, Wv2, Vt);
    attn    <<<1024, 128, 0, stream>>>(Q, K, Vt, Hf);
    prep_wt <<<  64, 256, 0, stream>>>(Wout, Wt);
    out_proj<<< 512, 256, 0, stream>>>(Hf, Wt, out);
}

// Round 4
// 121.295 us; speedup vs baseline: 1.3707x; 1.3707x over previous
//
#include <hip/hip_runtime.h>
#include <hip/hip_bf16.h>
#include <stdint.h>

#define T_SEQ 4096
#define NC96 43                 // ceil(4096/96) chunks of 96 kv

typedef float  f32x4   __attribute__((ext_vector_type(4)));
typedef float  f32x16  __attribute__((ext_vector_type(16)));
typedef short  bf16x8  __attribute__((ext_vector_type(8)));
typedef unsigned int u32x4 __attribute__((ext_vector_type(4)));

typedef const __attribute__((address_space(1))) uint32_t* gptr_t;
typedef __attribute__((address_space(3))) uint32_t* lptr_t;

__device__ __forceinline__ uint32_t f2bf1(float f) {
    uint32_t u = __float_as_uint(f);
    return (u + 0x7fffu + ((u >> 16) & 1u)) >> 16;   // RNE f32->bf16
}
__device__ __forceinline__ short f2bfs(float f) { return (short)f2bf1(f); }
__device__ __forceinline__ uint32_t cvtpk(float lo, float hi) {
    uint32_t r;
    asm("v_cvt_pk_bf16_f32 %0, %1, %2" : "=v"(r) : "v"(lo), "v"(hi));
    return r;
}

// ---------------------------------------------------------------------------
// Kernel 1: Q,K projections. Q pre-scaled by 0.125*log2(e) (softmax uses 2^x).
// Layout: [bh=b*2+h][t][64] bf16.
// ---------------------------------------------------------------------------
__global__ __launch_bounds__(256) void qk_proj(
    const float* __restrict__ x,
    const float* __restrict__ Wq1, const float* __restrict__ Wk1,
    const float* __restrict__ Wq2, const float* __restrict__ Wk2,
    short* __restrict__ Q, short* __restrict__ K)
{
    int idx = blockIdx.x * 256 + threadIdx.x;
    int d = idx & 63;
    int t = (idx >> 6) & (T_SEQ - 1);
    int b = idx >> 18;
    const float* xp = x + (size_t)(b * T_SEQ + t) * 6;
    float x0 = xp[0], x1 = xp[1], x2 = xp[2];
    float x3 = xp[3], x4 = xp[4], x5 = xp[5];
    const float QS = 0.125f * 1.44269504088896340736f;
    float q1 = (x0 * Wq1[d] + x1 * Wq1[64 + d] + x2 * Wq1[128 + d]) * QS;
    float k1 =  x0 * Wk1[d] + x1 * Wk1[64 + d] + x2 * Wk1[128 + d];
    float q2 = (x3 * Wq2[d] + x4 * Wq2[64 + d] + x5 * Wq2[128 + d]) * QS;
    float k2 =  x3 * Wk2[d] + x4 * Wk2[64 + d] + x5 * Wk2[128 + d];
    size_t base1 = ((size_t)(b * 2 + 0) * T_SEQ + t) * 64 + d;
    size_t base2 = ((size_t)(b * 2 + 1) * T_SEQ + t) * 64 + d;
    Q[base1] = f2bfs(q1);  Q[base2] = f2bfs(q2);
    K[base1] = f2bfs(k1);  K[base2] = f2bfs(k2);
}

// ---------------------------------------------------------------------------
// Kernel 2: V projection written FRAGMENT-MAJOR for attn's per-wave staging:
//   Vf[bh][c96][W(3)][m(4)][lane(64)][e(8)] bf16, where for element (t, d):
//     c = t/96, r = t%96, W = r>>5, kv32 = r&31,
//     half = kv32>>4, h = (kv32>>3)&1, e = kv32&7,
//     m = 2*(d>>5) + half, lane = (d&31) + 32*h.
//   Then attn's V stage for (bh, c, W) is 4 x 1KB CONTIGUOUS loads and the
//   LDS read is linear lane*16 (conflict-free). Fixes R2's 8KB-stride mess.
// ---------------------------------------------------------------------------
__global__ __launch_bounds__(256) void v_proj_t(
    const float* __restrict__ x,
    const float* __restrict__ Wv1, const float* __restrict__ Wv2,
    short* __restrict__ Vf)
{
    int bh = blockIdx.x >> 6;
    int tt = blockIdx.x & 63;
    int head = bh & 1, b = bh >> 1;
    int t  = tt * 64 + (threadIdx.x & 63);
    int dg = threadIdx.x >> 6;
    const float* Wv = head ? Wv2 : Wv1;
    const float* xp = x + (size_t)(b * T_SEQ + t) * 6 + head * 3;
    float x0 = xp[0], x1 = xp[1], x2 = xp[2];
    int c = t / 96;
    int r = t - c * 96;
    int W = r >> 5, kv32 = r & 31;
    int half = kv32 >> 4, h = (kv32 >> 3) & 1, e = kv32 & 7;
    size_t segbase = ((size_t)(bh * NC96 + c) * 3 + W) * 4 * 512;
    #pragma unroll
    for (int k = 0; k < 16; ++k) {
        int d = dg * 16 + k;
        float v = x0 * Wv[d] + x1 * Wv[64 + d] + x2 * Wv[128 + d];
        int m = ((d >> 5) << 1) + half;
        int lane = (d & 31) + 32 * h;
        Vf[segbase + (size_t)m * 512 + lane * 8 + e] = f2bfs(v);
    }
}

// ---------------------------------------------------------------------------
// Kernel 3: causal flash attention, FOLDED, 3-wave kv-split, PRIVATE waves.
//   R4: grid 1024 pairs (A=i, B=127-i), 192 threads = 3 waves; chunk = 96 kv,
//   wave W owns [kv0+32W, +31] for both tiles. All staging PER-WAVE PRIVATE:
//     - K: global_load_lds dbuf 2x4KB (own 32 rows, pre-swizzled source).
//     - V: fragment-major Vf -> 4x1KB contiguous global_load_lds, single
//       4KB buffer staged 1 chunk ahead (guarded by lgkmcnt(0) before
//       overwrite); LDS read linear lane*16, conflict-free.
//   12KB LDS/wave -> 36KB/block -> 4 blocks/CU; regs ~160/wave -> 12 waves/CU
//   (3/SIMD, up from R0's 2) AND critical wave does 43 chunks (vs R0's 64).
//   NO in-loop barriers: per-body counted `s_waitcnt vmcnt(4)` (each body
//   issues V(c+1) then K(c+2) = 8 loads; oldest 8 = chunk c's K + V).
//   Ghost kv (c=42,W=2 -> 4096..4127): K rows clamped to 4095, V segment
//   clamped to a WRITTEN segment (no NaN*0); values causally masked.
//   MASK RULE: mask iff kv0+32W+31 > t0X. Combine: R1's 3-partial tree.
// ---------------------------------------------------------------------------
__global__ __launch_bounds__(192, 3) void attn(
    const short* __restrict__ Q, const short* __restrict__ K,
    const short* __restrict__ Vt, float* __restrict__ Hf)
{
    __shared__ __align__(16) char smem[36864];  // 3 waves x 12KB; combine reuses

    int id = blockIdx.x;
    int xcd = id & 7, j = id >> 3;       // j 0..127
    int bh = xcd * 2 + (j & 1);          // 2 bh per XCD (L2 locality)
    int i  = j >> 1;                     // fold index 0..63
    int tid = threadIdx.x;
    int W = tid >> 6;                    // wave = kv-third (0..2)
    int lane = tid & 63;
    int ql = lane & 31, h = lane >> 5;
    int t0A = 32 * i, t0B = 32 * (127 - i);
    int qA = t0A + ql, qB = t0B + ql;
    int sweep = (t0B + 31) / 96 + 1;     // 96-kv chunks for tile B extent

    size_t kvbase = (size_t)bh * (T_SEQ * 64);
    char* wbase = smem + W * 12288;      // this wave's private LDS
    char* vbase = wbase + 8192;          // single V buffer (4KB)

    // Q fragments for both tiles (B-operand): lane holds Q[q][ks*16+h*8+j]
    bf16x8 qfA[4], qfB[4];
    #pragma unroll
    for (int ks = 0; ks < 4; ++ks) {
        qfA[ks] = *(const bf16x8*)(Q + kvbase + (size_t)qA * 64 + ks * 16 + h * 8);
        qfB[ks] = *(const bf16x8*)(Q + kvbase + (size_t)qB * 64 + ks * 16 + h * 8);
    }

    // K staging (per wave, own 32 rows): 64 lanes = 8 rows x 128B per instr.
    int r8 = lane >> 3;                  // 0..7
    int scol = ((lane & 7) ^ r8) * 8;    // pre-swizzled source column
    const short* ksrc0 = K + kvbase + scol;

    f32x16 accA0, accA1, accB0, accB1;
    #pragma unroll
    for (int r = 0; r < 16; ++r) { accA0[r]=0.f; accA1[r]=0.f; accB0[r]=0.f; accB1[r]=0.f; }
    float lA = 0.f, lB = 0.f;
    int swz = (ql & 7) << 4;

#define STAGEK(bsel, kvv)                                                       \
    {                                                                           \
        char* kb = wbase + (bsel) * 4096;                                       \
        _Pragma("unroll")                                                       \
        for (int z = 0; z < 4; ++z) {                                           \
            int srow = (kvv) + 32 * W + z * 8 + r8;                             \
            srow = srow > (T_SEQ - 1) ? (T_SEQ - 1) : srow;                     \
            __builtin_amdgcn_global_load_lds(                                   \
                (gptr_t)(ksrc0 + (size_t)srow * 64),                            \
                (lptr_t)(kb + z * 1024), 16, 0, 0);                             \
        }                                                                       \
    }

#define STAGEV(cc)                                                              \
    {                                                                           \
        int cs = (cc) > (NC96 - 1) ? (NC96 - 1) : (cc);                         \
        int Wv_ = (cs == NC96 - 1 && W == 2) ? 0 : W;  /* ghost -> written */   \
        const short* vs = Vt + ((size_t)(bh * NC96 + cs) * 3 + Wv_) * 4 * 512   \
                             + lane * 8;                                        \
        _Pragma("unroll")                                                       \
        for (int z = 0; z < 4; ++z)                                             \
            __builtin_amdgcn_global_load_lds(                                   \
                (gptr_t)(vs + z * 512), (lptr_t)(vbase + z * 1024), 16, 0, 0);  \
    }

#define QK_SM(qfX, qX, lX, pf0, pf1)                                            \
        {                                                                       \
            f32x16 Sv;                                                          \
            _Pragma("unroll") for (int r = 0; r < 16; ++r) Sv[r] = 0.f;         \
            Sv = __builtin_amdgcn_mfma_f32_32x32x16_bf16(kf0, qfX[0], Sv,0,0,0);\
            Sv = __builtin_amdgcn_mfma_f32_32x32x16_bf16(kf1, qfX[1], Sv,0,0,0);\
            Sv = __builtin_amdgcn_mfma_f32_32x32x16_bf16(kf2, qfX[2], Sv,0,0,0);\
            Sv = __builtin_amdgcn_mfma_f32_32x32x16_bf16(kf3, qfX[3], Sv,0,0,0);\
            bool needmask = (kv0 + 32 * W + 31 > (qX) - ql);  /* max_kv>t0X */  \
            uint32_t pw[8];                                                     \
            float l0 = 0.f, l1 = 0.f;                                           \
            _Pragma("unroll") for (int e = 0; e < 8; ++e) {                     \
                float p0 = __builtin_amdgcn_exp2f(Sv[2 * e]);                   \
                float p1 = __builtin_amdgcn_exp2f(Sv[2 * e + 1]);               \
                if (needmask) {                                                 \
                    int kv = kv0 + 32 * W + 4 * h + 2 * (e & 1) + 8 * (e >> 1); \
                    p0 = (kv     <= (qX)) ? p0 : 0.f;                           \
                    p1 = (kv + 1 <= (qX)) ? p1 : 0.f;                           \
                }                                                               \
                l0 += p0; l1 += p1;                                             \
                pw[e] = cvtpk(p0, p1);                                          \
            }                                                                   \
            lX += l0 + l1;                                                      \
            {                                                                   \
                uint32_t a0 = pw[0], b0 = pw[2], a1 = pw[1], b1 = pw[3];        \
                asm("v_permlane32_swap_b32 %0, %1" : "+v"(a0), "+v"(b0));       \
                asm("v_permlane32_swap_b32 %0, %1" : "+v"(a1), "+v"(b1));       \
                u32x4 fr = {a0, a1, b0, b1};                                    \
                pf0 = __builtin_bit_cast(bf16x8, fr);                           \
                uint32_t c0 = pw[4], d0 = pw[6], c1 = pw[5], d1 = pw[7];        \
                asm("v_permlane32_swap_b32 %0, %1" : "+v"(c0), "+v"(d0));       \
                asm("v_permlane32_swap_b32 %0, %1" : "+v"(c1), "+v"(d1));       \
                u32x4 fr1 = {c0, c1, d0, d1};                                   \
                pf1 = __builtin_bit_cast(bf16x8, fr1);                          \
            }                                                                   \
        }

#define BODY(cc)                                                                \
    {                                                                           \
        const int kv0 = 96 * (cc);                                              \
        asm volatile("s_waitcnt vmcnt(4)" ::: "memory");                        \
        const char* krow = wbase + ((cc) & 1) * 4096 + ql * 128;                \
        bf16x8 kf0 = *(const bf16x8*)(krow + ((0 * 32 + h * 16) ^ swz));        \
        bf16x8 kf1 = *(const bf16x8*)(krow + ((1 * 32 + h * 16) ^ swz));        \
        bf16x8 kf2 = *(const bf16x8*)(krow + ((2 * 32 + h * 16) ^ swz));        \
        bf16x8 kf3 = *(const bf16x8*)(krow + ((3 * 32 + h * 16) ^ swz));        \
        bool actA = (kv0 + 32 * W <= t0A + 31);                                 \
        bool actB = (kv0 + 32 * W <= t0B + 31);                                 \
        bf16x8 pfA0, pfA1, pfB0, pfB1;                                          \
        __builtin_amdgcn_s_setprio(1);                                          \
        if (actB) QK_SM(qfB, qB, lB, pfB0, pfB1)                                \
        if (actA) QK_SM(qfA, qA, lA, pfA0, pfA1)                                \
        bf16x8 vf00 = *(const bf16x8*)(vbase +    0 + lane * 16);               \
        bf16x8 vf01 = *(const bf16x8*)(vbase + 1024 + lane * 16);               \
        bf16x8 vf10 = *(const bf16x8*)(vbase + 2048 + lane * 16);               \
        bf16x8 vf11 = *(const bf16x8*)(vbase + 3072 + lane * 16);               \
        if (actB) {                                                             \
            accB0 = __builtin_amdgcn_mfma_f32_32x32x16_bf16(vf00, pfB0, accB0, 0, 0, 0); \
            accB0 = __builtin_amdgcn_mfma_f32_32x32x16_bf16(vf01, pfB1, accB0, 0, 0, 0); \
            accB1 = __builtin_amdgcn_mfma_f32_32x32x16_bf16(vf10, pfB0, accB1, 0, 0, 0); \
            accB1 = __builtin_amdgcn_mfma_f32_32x32x16_bf16(vf11, pfB1, accB1, 0, 0, 0); \
        }                                                                       \
        if (actA) {                                                             \
            accA0 = __builtin_amdgcn_mfma_f32_32x32x16_bf16(vf00, pfA0, accA0, 0, 0, 0); \
            accA0 = __builtin_amdgcn_mfma_f32_32x32x16_bf16(vf01, pfA1, accA0, 0, 0, 0); \
            accA1 = __builtin_amdgcn_mfma_f32_32x32x16_bf16(vf10, pfA0, accA1, 0, 0, 0); \
            accA1 = __builtin_amdgcn_mfma_f32_32x32x16_bf16(vf11, pfA1, accA1, 0, 0, 0); \
        }                                                                       \
        __builtin_amdgcn_s_setprio(0);                                          \
        asm volatile("s_waitcnt lgkmcnt(0)" ::: "memory");  /* V buf reads done */ \
        STAGEV((cc) + 1);                                                       \
        STAGEK((cc) & 1, kv0 + 192);                                            \
    }

    // Prologue: K0 -> buf0, V0 -> vbuf, K1 -> buf1  (queue: K0,V0,K1 = 12).
    STAGEK(0, 0);
    STAGEV(0);
    STAGEK(1, 96);

    for (int c = 0; c < sweep; ++c) BODY(c);
#undef BODY
#undef QK_SM
#undef STAGEV
#undef STAGEK

    // ---- cross-wave combine: 3 partials per tile, stride-33 (conflict-free)
    // Barrier first: main-loop LDS is reused; syncthreads' vmcnt(0) drain also
    // retires the in-flight ghost prefetches before the buffer is clobbered.
    __syncthreads();
    lA += __shfl_xor(lA, 32);
    lB += __shfl_xor(lB, 32);
    float* cb = (float*)smem;
    float* sA = cb + lane * 33;            // tile A segment [64][33]
    float* sB = cb + (64 + lane) * 33;     // tile B segment [64][33]

    // R1: wave2 publishes both tile partials
    if (W == 2) {
        #pragma unroll
        for (int g = 0; g < 4; ++g) {
            *(f32x4*)(sA + 4 * g)      = f32x4{accA0[4*g+0], accA0[4*g+1], accA0[4*g+2], accA0[4*g+3]};
            *(f32x4*)(sA + 16 + 4 * g) = f32x4{accA1[4*g+0], accA1[4*g+1], accA1[4*g+2], accA1[4*g+3]};
            *(f32x4*)(sB + 4 * g)      = f32x4{accB0[4*g+0], accB0[4*g+1], accB0[4*g+2], accB0[4*g+3]};
            *(f32x4*)(sB + 16 + 4 * g) = f32x4{accB1[4*g+0], accB1[4*g+1], accB1[4*g+2], accB1[4*g+3]};
        }
        sA[32] = lA;  sB[32] = lB;
    }
    __syncthreads();
    if (W == 0) {
        #pragma unroll
        for (int g = 0; g < 4; ++g) {
            f32x4 u0 = *(f32x4*)(sA + 4 * g);
            f32x4 u1 = *(f32x4*)(sA + 16 + 4 * g);
            accA0[4*g+0] += u0[0]; accA0[4*g+1] += u0[1]; accA0[4*g+2] += u0[2]; accA0[4*g+3] += u0[3];
            accA1[4*g+0] += u1[0]; accA1[4*g+1] += u1[1]; accA1[4*g+2] += u1[2]; accA1[4*g+3] += u1[3];
        }
        lA += sA[32];
    }
    if (W == 1) {
        #pragma unroll
        for (int g = 0; g < 4; ++g) {
            f32x4 u0 = *(f32x4*)(sB + 4 * g);
            f32x4 u1 = *(f32x4*)(sB + 16 + 4 * g);
            accB0[4*g+0] += u0[0]; accB0[4*g+1] += u0[1]; accB0[4*g+2] += u0[2]; accB0[4*g+3] += u0[3];
            accB1[4*g+0] += u1[0]; accB1[4*g+1] += u1[1]; accB1[4*g+2] += u1[2]; accB1[4*g+3] += u1[3];
        }
        lB += sB[32];
    }
    __syncthreads();
    // R2: wave0 publishes its B partial, wave1 its A partial
    if (W == 0) {
        #pragma unroll
        for (int g = 0; g < 4; ++g) {
            *(f32x4*)(sB + 4 * g)      = f32x4{accB0[4*g+0], accB0[4*g+1], accB0[4*g+2], accB0[4*g+3]};
            *(f32x4*)(sB + 16 + 4 * g) = f32x4{accB1[4*g+0], accB1[4*g+1], accB1[4*g+2], accB1[4*g+3]};
        }
        sB[32] = lB;
    }
    if (W == 1) {
        #pragma unroll
        for (int g = 0; g < 4; ++g) {
            *(f32x4*)(sA + 4 * g)      = f32x4{accA0[4*g+0], accA0[4*g+1], accA0[4*g+2], accA0[4*g+3]};
            *(f32x4*)(sA + 16 + 4 * g) = f32x4{accA1[4*g+0], accA1[4*g+1], accA1[4*g+2], accA1[4*g+3]};
        }
        sA[32] = lA;
    }
    __syncthreads();
    if (W < 2) {
        f32x16 a0, a1;
        float lf;
        if (W == 0) {
            #pragma unroll
            for (int g = 0; g < 4; ++g) {
                f32x4 u0 = *(f32x4*)(sA + 4 * g);
                f32x4 u1 = *(f32x4*)(sA + 16 + 4 * g);
                accA0[4*g+0] += u0[0]; accA0[4*g+1] += u0[1]; accA0[4*g+2] += u0[2]; accA0[4*g+3] += u0[3];
                accA1[4*g+0] += u1[0]; accA1[4*g+1] += u1[1]; accA1[4*g+2] += u1[2]; accA1[4*g+3] += u1[3];
            }
            lf = lA + sA[32];
            a0 = accA0; a1 = accA1;
        } else {
            #pragma unroll
            for (int g = 0; g < 4; ++g) {
                f32x4 u0 = *(f32x4*)(sB + 4 * g);
                f32x4 u1 = *(f32x4*)(sB + 16 + 4 * g);
                accB0[4*g+0] += u0[0]; accB0[4*g+1] += u0[1]; accB0[4*g+2] += u0[2]; accB0[4*g+3] += u0[3];
                accB1[4*g+0] += u1[0]; accB1[4*g+1] += u1[1]; accB1[4*g+2] += u1[2]; accB1[4*g+3] += u1[3];
            }
            lf = lB + sB[32];
            a0 = accB0; a1 = accB1;
        }
        float rl = 1.0f / lf;
        int t0 = W ? t0B : t0A;
        int head = bh & 1, b = bh >> 1;
        float* hp = Hf + ((size_t)(b * T_SEQ) + t0 + ql) * 128 + head * 64 + 4 * h;
        #pragma unroll
        for (int g2 = 0; g2 < 4; ++g2) {
            f32x4 s0 = { a0[g2*4+0]*rl, a0[g2*4+1]*rl, a0[g2*4+2]*rl, a0[g2*4+3]*rl };
            *(f32x4*)(hp + 8 * g2) = s0;               // d = 8*g2+4h+0..3
            f32x4 s1 = { a1[g2*4+0]*rl, a1[g2*4+1]*rl, a1[g2*4+2]*rl, a1[g2*4+3]*rl };
            *(f32x4*)(hp + 32 + 8 * g2) = s1;          // d = 32+8*g2+4h+0..3
        }
    }
}

// ---------------------------------------------------------------------------
// Kernel 4a: one-shot Wout -> Wt bf16, transposed + xor-swizzled for LDS.
// ---------------------------------------------------------------------------
__global__ __launch_bounds__(256) void prep_wt(
    const float* __restrict__ Wout, short* __restrict__ Wt)
{
    int tid = blockIdx.x * 256 + threadIdx.x;   // 16384
    int j = tid >> 7, k = tid & 127;
    float v = Wout[k * 128 + j];
    int slot = k >> 3;
    Wt[j * 128 + (((slot ^ (j & 7)) << 3) | (k & 7))] = f2bfs(v);
}

// ---------------------------------------------------------------------------
// Kernel 4b: out = H(32768x128 f32, in d_out) @ Wout -> f32 (in place).
// Row-block-diagonal: each wave reads only its own 16 rows before writing.
// ---------------------------------------------------------------------------
__global__ __launch_bounds__(256) void out_proj(
    const float* Hf, const short* __restrict__ Wt, float* out)
{
    __shared__ __align__(16) char lws[32768];
    int tid = threadIdx.x;
    int w = tid >> 6, lane = tid & 63, c = lane & 15, g = lane >> 4;
    int cs = c & 7;
    #pragma unroll
    for (int z = 0; z < 8; ++z)
        __builtin_amdgcn_global_load_lds((gptr_t)(Wt + z * 2048 + w * 512 + lane * 8),
                                         (lptr_t)(lws + z * 4096 + w * 1024), 16, 0, 0);
    __syncthreads();

    int row0 = blockIdx.x * 64 + w * 16;
    bf16x8 af[4];
    const float* hp = Hf + (size_t)(row0 + c) * 128 + g * 8;
    #pragma unroll
    for (int kc = 0; kc < 4; ++kc) {
        f32x4 x0 = *(const f32x4*)(hp + kc * 32);
        f32x4 x1 = *(const f32x4*)(hp + kc * 32 + 4);
        u32x4 wv = { cvtpk(x0[0], x0[1]), cvtpk(x0[2], x0[3]),
                     cvtpk(x1[0], x1[1]), cvtpk(x1[2], x1[3]) };
        af[kc] = __builtin_bit_cast(bf16x8, wv);
    }
    #pragma unroll
    for (int jt = 0; jt < 8; ++jt) {
        f32x4 accum = {0.f, 0.f, 0.f, 0.f};
        #pragma unroll
        for (int kc = 0; kc < 4; ++kc) {
            int row = jt * 16 + c;
            bf16x8 bfr = *(const bf16x8*)(lws + row * 256 + (((kc * 4 + g) ^ cs) << 4));
            accum = __builtin_amdgcn_mfma_f32_16x16x32_bf16(af[kc], bfr, accum, 0, 0, 0);
        }
        #pragma unroll
        for (int r = 0; r < 4; ++r)
            out[(size_t)(row0 + g * 4 + r) * 128 + jt * 16 + c] = accum[r];
    }
}

// ---------------------------------------------------------------------------
extern "C" void kernel_launch(void* const* d_in, const int* in_sizes, int n_in,
                              void* d_out, int out_size, void* d_ws, size_t ws_size,
                              hipStream_t stream)
{
    (void)in_sizes; (void)n_in; (void)out_size; (void)ws_size;
    const float* x    = (const float*)d_in[0];
    const float* Wq1  = (const float*)d_in[1];
    const float* Wk1  = (const float*)d_in[2];
    const float* Wv1  = (const float*)d_in[3];
    const float* Wq2  = (const float*)d_in[4];
    const float* Wk2  = (const float*)d_in[5];
    const float* Wv2  = (const float*)d_in[6];
    const float* Wout = (const float*)d_in[7];
    float* out = (float*)d_out;

    char* ws = (char*)d_ws;
    short* Q  = (short*)(ws);                               // 8 MiB (dead after attn)
    short* K  = (short*)(ws + (size_t)8  * 1024 * 1024);    // 8 MiB
    short* Vf = (short*)(ws + (size_t)16 * 1024 * 1024);    // 8.07 MiB (43 chunks)
    short* Wt = Q;                                          // reuse Q region
    float* Hf = out;                                        // f32 H lives in d_out

    qk_proj <<<8192, 256, 0, stream>>>(x, Wq1, Wk1, Wq2, Wk2, Q, K);
    v_proj_t<<<1024, 256, 0, stream>>>(x, Wv1, Wv2, Vf);
    attn    <<<1024, 192, 0, stream>>>(Q, K, Vf, Hf);
    prep_wt <<<  64, 256, 0, stream>>>(Wout, Wt);
    out_proj<<< 512, 256, 0, stream>>>(Hf, Wt, out);
}

// Round 5
// 97.522 us; speedup vs baseline: 1.7049x; 1.2438x over previous
//
#include <hip/hip_runtime.h>
#include <hip/hip_bf16.h>
#include <stdint.h>

#define T_SEQ 4096

typedef float  f32x4   __attribute__((ext_vector_type(4)));
typedef float  f32x16  __attribute__((ext_vector_type(16)));
typedef short  bf16x8  __attribute__((ext_vector_type(8)));
typedef unsigned int u32x4 __attribute__((ext_vector_type(4)));

typedef const __attribute__((address_space(1))) uint32_t* gptr_t;
typedef __attribute__((address_space(3))) uint32_t* lptr_t;

__device__ __forceinline__ uint32_t f2bf1(float f) {
    uint32_t u = __float_as_uint(f);
    return (u + 0x7fffu + ((u >> 16) & 1u)) >> 16;   // RNE f32->bf16
}
__device__ __forceinline__ short f2bfs(float f) { return (short)f2bf1(f); }
__device__ __forceinline__ uint32_t cvtpk(float lo, float hi) {
    uint32_t r;
    asm("v_cvt_pk_bf16_f32 %0, %1, %2" : "=v"(r) : "v"(lo), "v"(hi));
    return r;
}

// ---------------------------------------------------------------------------
// Kernel 1: Q,K projections. Q pre-scaled by 0.125*log2(e) (softmax uses 2^x).
// Layout: [bh=b*2+h][t][64] bf16.
// ---------------------------------------------------------------------------
__global__ __launch_bounds__(256) void qk_proj(
    const float* __restrict__ x,
    const float* __restrict__ Wq1, const float* __restrict__ Wk1,
    const float* __restrict__ Wq2, const float* __restrict__ Wk2,
    short* __restrict__ Q, short* __restrict__ K)
{
    int idx = blockIdx.x * 256 + threadIdx.x;
    int d = idx & 63;
    int t = (idx >> 6) & (T_SEQ - 1);
    int b = idx >> 18;
    const float* xp = x + (size_t)(b * T_SEQ + t) * 6;
    float x0 = xp[0], x1 = xp[1], x2 = xp[2];
    float x3 = xp[3], x4 = xp[4], x5 = xp[5];
    const float QS = 0.125f * 1.44269504088896340736f;
    float q1 = (x0 * Wq1[d] + x1 * Wq1[64 + d] + x2 * Wq1[128 + d]) * QS;
    float k1 =  x0 * Wk1[d] + x1 * Wk1[64 + d] + x2 * Wk1[128 + d];
    float q2 = (x3 * Wq2[d] + x4 * Wq2[64 + d] + x5 * Wq2[128 + d]) * QS;
    float k2 =  x3 * Wk2[d] + x4 * Wk2[64 + d] + x5 * Wk2[128 + d];
    size_t base1 = ((size_t)(b * 2 + 0) * T_SEQ + t) * 64 + d;
    size_t base2 = ((size_t)(b * 2 + 1) * T_SEQ + t) * 64 + d;
    Q[base1] = f2bfs(q1);  Q[base2] = f2bfs(q2);
    K[base1] = f2bfs(k1);  K[base2] = f2bfs(k2);
}

// ---------------------------------------------------------------------------
// Kernel 2: V projection written TRANSPOSED: Vt[bh][d][t] bf16. (R0 layout)
// ---------------------------------------------------------------------------
__global__ __launch_bounds__(256) void v_proj_t(
    const float* __restrict__ x,
    const float* __restrict__ Wv1, const float* __restrict__ Wv2,
    short* __restrict__ Vt)
{
    int bh = blockIdx.x >> 6;
    int tt = blockIdx.x & 63;
    int head = bh & 1, b = bh >> 1;
    int t  = tt * 64 + (threadIdx.x & 63);
    int dg = threadIdx.x >> 6;
    const float* Wv = head ? Wv2 : Wv1;
    const float* xp = x + (size_t)(b * T_SEQ + t) * 6 + head * 3;
    float x0 = xp[0], x1 = xp[1], x2 = xp[2];
    size_t base = (size_t)bh * 64 * T_SEQ + t;
    #pragma unroll
    for (int k = 0; k < 16; ++k) {
        int d = dg * 16 + k;
        float v = x0 * Wv[d] + x1 * Wv[64 + d] + x2 * Wv[128 + d];
        Vt[base + (size_t)d * T_SEQ] = f2bfs(v);
    }
}

// ---------------------------------------------------------------------------
// Kernel 3: causal flash attention, LOOP-LENGTH-BALANCED.
//   R5 diagnosis: R0's wall was block imbalance (loop len = far-tile extent,
//   33..64 iters; occupancy ratio 0.71 = avg/max iters; latency-bound so a
//   1-tile iter costs the same as a 2-tile iter). Fix the schedule, keep the
//   per-wave math byte-identical to R0:
//   - ADJACENT pairs (2p, 2p+1) have EQUAL extents (⌈(p+1)/2⌉ 128-kv chunks)
//     -> every iteration double-active.
//   - Each block runs TWO pairs sequentially: (126-2m,127-2m) then (2m,2m+1)
//     -> iterations = ⌈(64-m)/2⌉ + ⌈(m+1)/2⌉ = 33 for EVERY block.
//   - 512 blocks x 4 waves; chunk = 128 kv; wave W owns [kv0+32W,+31] for
//     both live tiles. LDS 64KB/block (K 16K + V 16K, dbuf) -> 2 blocks/CU,
//     8 waves/CU (= R0 residency). No clamps: staged kv never exceeds 4095.
//   - V LDS rows 256B, (d&15) XOR swizzle -> 2-way conflicts (R0 V was 4-way).
//   - Per-iteration __syncthreads (R0 discipline); 2 combines (mid + final),
//     4 partials/tile via stride-33 LDS tree in a free 32KB buffer.
// ---------------------------------------------------------------------------
__global__ __launch_bounds__(256, 2) void attn(
    const short* __restrict__ Q, const short* __restrict__ K,
    const short* __restrict__ Vt, float* __restrict__ Hf)
{
    __shared__ __align__(16) char smem[65536];   // 2 x (K 16K + V 16K)

    int id = blockIdx.x;                 // 512 blocks
    int xcd = id & 7, j = id >> 3;       // j 0..63
    int bh = xcd * 2 + (j & 1);          // 2 bh per XCD (L2 locality)
    int m  = j >> 1;                     // 0..31
    int tid = threadIdx.x;
    int W = tid >> 6;                    // wave = kv quarter (0..3)
    int lane = tid & 63;
    int ql = lane & 31, h = lane >> 5;
    int head = bh & 1, bb = bh >> 1;

    int n1 = (65 - m) >> 1;              // ceil((64-m)/2)
    int n2 = (m + 2) >> 1;               // ceil((m+1)/2)   (n1+n2 = 33)

    size_t kvbase = (size_t)bh * (T_SEQ * 64);

    // K staging map: per instr z, 32 rows x 128B; thread -> row tid>>3, slot tid&7
    int krl = tid >> 3;
    int kcol = ((tid & 7) ^ (krl & 7)) * 8;
    const short* ksrc0 = K + kvbase + (size_t)krl * 64 + kcol;
    // V staging map: per instr z, 16 d-rows x 256B; thread -> row tid>>4, slot tid&15
    int vrl = tid >> 4;
    int vcol = ((tid & 15) ^ (vrl & 15)) * 8;
    const short* vsrc0 = Vt + kvbase + (size_t)vrl * T_SEQ + vcol;

    f32x16 accE0, accE1, accO0, accO1;
    #pragma unroll
    for (int r = 0; r < 16; ++r) { accE0[r]=0.f; accE1[r]=0.f; accO0[r]=0.f; accO1[r]=0.f; }
    float lE = 0.f, lO = 0.f;
    int swz8  = (ql & 7) << 4;
    int swz16 = (ql & 15) << 4;

    int t0E, t0O, qE, qO;
    bf16x8 qfE[4], qfO[4];

#define LOADQ()                                                                 \
    _Pragma("unroll")                                                           \
    for (int ks = 0; ks < 4; ++ks) {                                            \
        qfE[ks] = *(const bf16x8*)(Q + kvbase + (size_t)qE * 64 + ks * 16 + h * 8); \
        qfO[ks] = *(const bf16x8*)(Q + kvbase + (size_t)qO * 64 + ks * 16 + h * 8); \
    }

#define STAGE(bsel, kvv)                                                        \
    {                                                                           \
        char* kb = smem + (bsel) * 32768;                                       \
        char* vb = kb + 16384;                                                  \
        _Pragma("unroll")                                                       \
        for (int z = 0; z < 4; ++z)                                             \
            __builtin_amdgcn_global_load_lds(                                   \
                (gptr_t)(ksrc0 + (size_t)((kvv) + 32 * z) * 64),                \
                (lptr_t)(kb + z * 4096 + W * 1024), 16, 0, 0);                  \
        _Pragma("unroll")                                                       \
        for (int z = 0; z < 4; ++z)                                             \
            __builtin_amdgcn_global_load_lds(                                   \
                (gptr_t)(vsrc0 + (size_t)(16 * z) * T_SEQ + (kvv)),             \
                (lptr_t)(vb + z * 4096 + W * 1024), 16, 0, 0);                  \
    }

#define QK_SM(qfX, qX, lX, pf0, pf1)                                            \
        {                                                                       \
            f32x16 Sv;                                                          \
            _Pragma("unroll") for (int r = 0; r < 16; ++r) Sv[r] = 0.f;         \
            Sv = __builtin_amdgcn_mfma_f32_32x32x16_bf16(kf0, qfX[0], Sv,0,0,0);\
            Sv = __builtin_amdgcn_mfma_f32_32x32x16_bf16(kf1, qfX[1], Sv,0,0,0);\
            Sv = __builtin_amdgcn_mfma_f32_32x32x16_bf16(kf2, qfX[2], Sv,0,0,0);\
            Sv = __builtin_amdgcn_mfma_f32_32x32x16_bf16(kf3, qfX[3], Sv,0,0,0);\
            bool needmask = (kv0 + 32 * W + 31 > (qX) - ql);  /* max_kv>t0X */  \
            uint32_t pw[8];                                                     \
            float l0 = 0.f, l1 = 0.f;                                           \
            _Pragma("unroll") for (int e = 0; e < 8; ++e) {                     \
                float p0 = __builtin_amdgcn_exp2f(Sv[2 * e]);                   \
                float p1 = __builtin_amdgcn_exp2f(Sv[2 * e + 1]);               \
                if (needmask) {                                                 \
                    int kv = kv0 + 32 * W + 4 * h + 2 * (e & 1) + 8 * (e >> 1); \
                    p0 = (kv     <= (qX)) ? p0 : 0.f;                           \
                    p1 = (kv + 1 <= (qX)) ? p1 : 0.f;                           \
                }                                                               \
                l0 += p0; l1 += p1;                                             \
                pw[e] = cvtpk(p0, p1);                                          \
            }                                                                   \
            lX += l0 + l1;                                                      \
            {                                                                   \
                uint32_t a0 = pw[0], b0 = pw[2], a1 = pw[1], b1 = pw[3];        \
                asm("v_permlane32_swap_b32 %0, %1" : "+v"(a0), "+v"(b0));       \
                asm("v_permlane32_swap_b32 %0, %1" : "+v"(a1), "+v"(b1));       \
                u32x4 fr = {a0, a1, b0, b1};                                    \
                pf0 = __builtin_bit_cast(bf16x8, fr);                           \
                uint32_t c0 = pw[4], d0 = pw[6], c1 = pw[5], d1 = pw[7];        \
                asm("v_permlane32_swap_b32 %0, %1" : "+v"(c0), "+v"(d0));       \
                asm("v_permlane32_swap_b32 %0, %1" : "+v"(c1), "+v"(d1));       \
                u32x4 fr1 = {c0, c1, d0, d1};                                   \
                pf1 = __builtin_bit_cast(bf16x8, fr1);                          \
            }                                                                   \
        }

#define PV(a0, a1, p0, p1)                                                      \
    {                                                                           \
        a0 = __builtin_amdgcn_mfma_f32_32x32x16_bf16(vf00, p0, a0, 0, 0, 0);    \
        a0 = __builtin_amdgcn_mfma_f32_32x32x16_bf16(vf01, p1, a0, 0, 0, 0);    \
        a1 = __builtin_amdgcn_mfma_f32_32x32x16_bf16(vf10, p0, a1, 0, 0, 0);    \
        a1 = __builtin_amdgcn_mfma_f32_32x32x16_bf16(vf11, p1, a1, 0, 0, 0);    \
    }

#define BODY(bsel, kv0v, do_stage, nkv)                                         \
    {                                                                           \
        const int kv0 = (kv0v);                                                 \
        if (do_stage) STAGE((bsel) ^ 1, nkv);                                   \
        const char* kb = smem + (bsel) * 32768;                                 \
        const char* vb = kb + 16384;                                            \
        const char* krw = kb + (32 * W + ql) * 128;                             \
        bf16x8 kf0 = *(const bf16x8*)(krw + ((0 * 32 + h * 16) ^ swz8));        \
        bf16x8 kf1 = *(const bf16x8*)(krw + ((1 * 32 + h * 16) ^ swz8));        \
        bf16x8 kf2 = *(const bf16x8*)(krw + ((2 * 32 + h * 16) ^ swz8));        \
        bf16x8 kf3 = *(const bf16x8*)(krw + ((3 * 32 + h * 16) ^ swz8));        \
        bool actE = (kv0 + 32 * W <= t0E + 31);                                 \
        bool actO = (kv0 + 32 * W <= t0O + 31);                                 \
        bf16x8 pfE0, pfE1, pfO0, pfO1;                                          \
        __builtin_amdgcn_s_setprio(1);                                          \
        if (actO) QK_SM(qfO, qO, lO, pfO0, pfO1)                                \
        if (actE) QK_SM(qfE, qE, lE, pfE0, pfE1)                                \
        const char* vr0 = vb + ql * 256;                                        \
        const char* vr1 = vb + (32 + ql) * 256;                                 \
        int vc0 = (64 * W + 16 * h) ^ swz16;                                    \
        int vc1 = (64 * W + 32 + 16 * h) ^ swz16;                               \
        bf16x8 vf00 = *(const bf16x8*)(vr0 + vc0);                              \
        bf16x8 vf01 = *(const bf16x8*)(vr0 + vc1);                              \
        bf16x8 vf10 = *(const bf16x8*)(vr1 + vc0);                              \
        bf16x8 vf11 = *(const bf16x8*)(vr1 + vc1);                              \
        if (actO) PV(accO0, accO1, pfO0, pfO1)                                  \
        if (actE) PV(accE0, accE1, pfE0, pfE1)                                  \
        __builtin_amdgcn_s_setprio(0);                                          \
        __syncthreads();                                                        \
    }

#define PUB(R, a0, a1, lv)                                                      \
    {                                                                           \
        float* pb = (R) + lane * 33;                                            \
        _Pragma("unroll")                                                       \
        for (int g = 0; g < 4; ++g) {                                           \
            *(f32x4*)(pb + 4 * g)      = f32x4{(a0)[4*g+0],(a0)[4*g+1],(a0)[4*g+2],(a0)[4*g+3]}; \
            *(f32x4*)(pb + 16 + 4 * g) = f32x4{(a1)[4*g+0],(a1)[4*g+1],(a1)[4*g+2],(a1)[4*g+3]}; \
        }                                                                       \
        pb[32] = (lv);                                                          \
    }

#define ABS(R, a0, a1, lv)                                                      \
    {                                                                           \
        float* pb = (R) + lane * 33;                                            \
        _Pragma("unroll")                                                       \
        for (int g = 0; g < 4; ++g) {                                           \
            f32x4 u0 = *(f32x4*)(pb + 4 * g);                                   \
            f32x4 u1 = *(f32x4*)(pb + 16 + 4 * g);                              \
            (a0)[4*g+0]+=u0[0]; (a0)[4*g+1]+=u0[1]; (a0)[4*g+2]+=u0[2]; (a0)[4*g+3]+=u0[3]; \
            (a1)[4*g+0]+=u1[0]; (a1)[4*g+1]+=u1[1]; (a1)[4*g+2]+=u1[2]; (a1)[4*g+3]+=u1[3]; \
        }                                                                       \
        (lv) += pb[32];                                                         \
    }

#define WRITEH(a0, a1, lv, t0X)                                                 \
    {                                                                           \
        float rl = 1.0f / (lv);                                                 \
        float* hp = Hf + ((size_t)(bb * T_SEQ) + (t0X) + ql) * 128 + head * 64 + 4 * h; \
        _Pragma("unroll")                                                       \
        for (int g2 = 0; g2 < 4; ++g2) {                                        \
            f32x4 s0 = { (a0)[g2*4+0]*rl, (a0)[g2*4+1]*rl, (a0)[g2*4+2]*rl, (a0)[g2*4+3]*rl }; \
            *(f32x4*)(hp + 8 * g2) = s0;                                        \
            f32x4 s1 = { (a1)[g2*4+0]*rl, (a1)[g2*4+1]*rl, (a1)[g2*4+2]*rl, (a1)[g2*4+3]*rl }; \
            *(f32x4*)(hp + 32 + 8 * g2) = s1;                                   \
        }                                                                       \
    }

#define COMBINE(scratchp)                                                       \
    {                                                                           \
        __syncthreads();                                                        \
        lE += __shfl_xor(lE, 32);  lO += __shfl_xor(lO, 32);                    \
        float* Ar = (float*)(scratchp);                                         \
        float* Br = Ar + 64 * 33;                                               \
        if (W == 2) PUB(Ar, accE0, accE1, lE)                                   \
        if (W == 3) PUB(Br, accE0, accE1, lE)                                   \
        __syncthreads();                                                        \
        if (W == 0) { ABS(Ar, accE0, accE1, lE) ABS(Br, accE0, accE1, lE) }     \
        __syncthreads();                                                        \
        if (W == 2) PUB(Ar, accO0, accO1, lO)                                   \
        if (W == 3) PUB(Br, accO0, accO1, lO)                                   \
        __syncthreads();                                                        \
        if (W == 1) { ABS(Ar, accO0, accO1, lO) ABS(Br, accO0, accO1, lO) }     \
        __syncthreads();                                                        \
        if (W == 1) PUB(Ar, accE0, accE1, lE)                                   \
        if (W == 0) PUB(Br, accO0, accO1, lO)                                   \
        __syncthreads();                                                        \
        if (W == 0) { ABS(Ar, accE0, accE1, lE) WRITEH(accE0, accE1, lE, t0E) } \
        if (W == 1) { ABS(Br, accO0, accO1, lO) WRITEH(accO0, accO1, lO, t0O) } \
        __syncthreads();                                                        \
    }

    // ================= phase 1: pair (126-2m, 127-2m) =================
    t0E = 32 * (126 - 2 * m);  t0O = t0E + 32;
    qE = t0E + ql;  qO = t0O + ql;
    LOADQ();
    STAGE(0, 0);
    __syncthreads();
    for (int c = 0; c < n1; ++c)
        BODY(c & 1, 128 * c, 1, (c + 1 < n1) ? 128 * (c + 1) : 0);
    // last iter staged phase-2 chunk0 into buffer (n1&1); scratch = other buf
    COMBINE(smem + ((n1 - 1) & 1) * 32768);

    // ================= phase 2: pair (2m, 2m+1) =================
    t0E = 64 * m;  t0O = t0E + 32;
    qE = t0E + ql;  qO = t0O + ql;
    LOADQ();
    #pragma unroll
    for (int r = 0; r < 16; ++r) { accE0[r]=0.f; accE1[r]=0.f; accO0[r]=0.f; accO1[r]=0.f; }
    lE = 0.f;  lO = 0.f;
    for (int c = 0; c < n2; ++c)
        BODY((n1 + c) & 1, 128 * c, (c + 1 < n2), 128 * (c + 1));
    COMBINE(smem + ((n1 + n2 - 1) & 1) * 32768);

#undef COMBINE
#undef WRITEH
#undef ABS
#undef PUB
#undef BODY
#undef PV
#undef QK_SM
#undef STAGE
#undef LOADQ
}

// ---------------------------------------------------------------------------
// Kernel 4a: one-shot Wout -> Wt bf16, transposed + xor-swizzled for LDS.
// ---------------------------------------------------------------------------
__global__ __launch_bounds__(256) void prep_wt(
    const float* __restrict__ Wout, short* __restrict__ Wt)
{
    int tid = blockIdx.x * 256 + threadIdx.x;   // 16384
    int j = tid >> 7, k = tid & 127;
    float v = Wout[k * 128 + j];
    int slot = k >> 3;
    Wt[j * 128 + (((slot ^ (j & 7)) << 3) | (k & 7))] = f2bfs(v);
}

// ---------------------------------------------------------------------------
// Kernel 4b: out = H(32768x128 f32, in d_out) @ Wout -> f32 (in place).
// Row-block-diagonal: each wave reads only its own 16 rows before writing.
// ---------------------------------------------------------------------------
__global__ __launch_bounds__(256) void out_proj(
    const float* Hf, const short* __restrict__ Wt, float* out)
{
    __shared__ __align__(16) char lws[32768];
    int tid = threadIdx.x;
    int w = tid >> 6, lane = tid & 63, c = lane & 15, g = lane >> 4;
    int cs = c & 7;
    #pragma unroll
    for (int z = 0; z < 8; ++z)
        __builtin_amdgcn_global_load_lds((gptr_t)(Wt + z * 2048 + w * 512 + lane * 8),
                                         (lptr_t)(lws + z * 4096 + w * 1024), 16, 0, 0);
    __syncthreads();

    int row0 = blockIdx.x * 64 + w * 16;
    bf16x8 af[4];
    const float* hp = Hf + (size_t)(row0 + c) * 128 + g * 8;
    #pragma unroll
    for (int kc = 0; kc < 4; ++kc) {
        f32x4 x0 = *(const f32x4*)(hp + kc * 32);
        f32x4 x1 = *(const f32x4*)(hp + kc * 32 + 4);
        u32x4 wv = { cvtpk(x0[0], x0[1]), cvtpk(x0[2], x0[3]),
                     cvtpk(x1[0], x1[1]), cvtpk(x1[2], x1[3]) };
        af[kc] = __builtin_bit_cast(bf16x8, wv);
    }
    #pragma unroll
    for (int jt = 0; jt < 8; ++jt) {
        f32x4 accum = {0.f, 0.f, 0.f, 0.f};
        #pragma unroll
        for (int kc = 0; kc < 4; ++kc) {
            int row = jt * 16 + c;
            bf16x8 bfr = *(const bf16x8*)(lws + row * 256 + (((kc * 4 + g) ^ cs) << 4));
            accum = __builtin_amdgcn_mfma_f32_16x16x32_bf16(af[kc], bfr, accum, 0, 0, 0);
        }
        #pragma unroll
        for (int r = 0; r < 4; ++r)
            out[(size_t)(row0 + g * 4 + r) * 128 + jt * 16 + c] = accum[r];
    }
}

// ---------------------------------------------------------------------------
extern "C" void kernel_launch(void* const* d_in, const int* in_sizes, int n_in,
                              void* d_out, int out_size, void* d_ws, size_t ws_size,
                              hipStream_t stream)
{
    (void)in_sizes; (void)n_in; (void)out_size; (void)ws_size;
    const float* x    = (const float*)d_in[0];
    const float* Wq1  = (const float*)d_in[1];
    const float* Wk1  = (const float*)d_in[2];
    const float* Wv1  = (const float*)d_in[3];
    const float* Wq2  = (const float*)d_in[4];
    const float* Wk2  = (const float*)d_in[5];
    const float* Wv2  = (const float*)d_in[6];
    const float* Wout = (const float*)d_in[7];
    float* out = (float*)d_out;

    char* ws = (char*)d_ws;
    short* Q  = (short*)(ws);                               // 8 MiB (dead after attn)
    short* K  = (short*)(ws + (size_t)8  * 1024 * 1024);    // 8 MiB
    short* Vt = (short*)(ws + (size_t)16 * 1024 * 1024);    // 8 MiB
    short* Wt = Q;                                          // reuse Q region
    float* Hf = out;                                        // f32 H lives in d_out

    qk_proj <<<8192, 256, 0, stream>>>(x, Wq1, Wk1, Wq2, Wk2, Q, K);
    v_proj_t<<<1024, 256, 0, stream>>>(x, Wv1, Wv2, Vt);
    attn    <<< 512, 256, 0, stream>>>(Q, K, Vt, Hf);
    prep_wt <<<  64, 256, 0, stream>>>(Wout, Wt);
    out_proj<<< 512, 256, 0, stream>>>(Hf, Wt, out);
}

// Round 6
// 96.630 us; speedup vs baseline: 1.7206x; 1.0092x over previous
//
#include <hip/hip_runtime.h>
#include <hip/hip_bf16.h>
#include <stdint.h>

#define T_SEQ 4096

typedef float  f32x4   __attribute__((ext_vector_type(4)));
typedef float  f32x16  __attribute__((ext_vector_type(16)));
typedef short  bf16x8  __attribute__((ext_vector_type(8)));
typedef unsigned int u32x4 __attribute__((ext_vector_type(4)));

typedef const __attribute__((address_space(1))) uint32_t* gptr_t;
typedef __attribute__((address_space(3))) uint32_t* lptr_t;

__device__ __forceinline__ uint32_t f2bf1(float f) {
    uint32_t u = __float_as_uint(f);
    return (u + 0x7fffu + ((u >> 16) & 1u)) >> 16;   // RNE f32->bf16
}
__device__ __forceinline__ short f2bfs(float f) { return (short)f2bf1(f); }
__device__ __forceinline__ uint32_t cvtpk(float lo, float hi) {
    uint32_t r;
    asm("v_cvt_pk_bf16_f32 %0, %1, %2" : "=v"(r) : "v"(lo), "v"(hi));
    return r;
}

// ---------------------------------------------------------------------------
// Kernel 1: Q,K projections. Q pre-scaled by 0.125*log2(e) (softmax uses 2^x).
// Layout: [bh=b*2+h][t][64] bf16.
// ---------------------------------------------------------------------------
__global__ __launch_bounds__(256) void qk_proj(
    const float* __restrict__ x,
    const float* __restrict__ Wq1, const float* __restrict__ Wk1,
    const float* __restrict__ Wq2, const float* __restrict__ Wk2,
    short* __restrict__ Q, short* __restrict__ K)
{
    int idx = blockIdx.x * 256 + threadIdx.x;
    int d = idx & 63;
    int t = (idx >> 6) & (T_SEQ - 1);
    int b = idx >> 18;
    const float* xp = x + (size_t)(b * T_SEQ + t) * 6;
    float x0 = xp[0], x1 = xp[1], x2 = xp[2];
    float x3 = xp[3], x4 = xp[4], x5 = xp[5];
    const float QS = 0.125f * 1.44269504088896340736f;
    float q1 = (x0 * Wq1[d] + x1 * Wq1[64 + d] + x2 * Wq1[128 + d]) * QS;
    float k1 =  x0 * Wk1[d] + x1 * Wk1[64 + d] + x2 * Wk1[128 + d];
    float q2 = (x3 * Wq2[d] + x4 * Wq2[64 + d] + x5 * Wq2[128 + d]) * QS;
    float k2 =  x3 * Wk2[d] + x4 * Wk2[64 + d] + x5 * Wk2[128 + d];
    size_t base1 = ((size_t)(b * 2 + 0) * T_SEQ + t) * 64 + d;
    size_t base2 = ((size_t)(b * 2 + 1) * T_SEQ + t) * 64 + d;
    Q[base1] = f2bfs(q1);  Q[base2] = f2bfs(q2);
    K[base1] = f2bfs(k1);  K[base2] = f2bfs(k2);
}

// ---------------------------------------------------------------------------
// Kernel 2: V projection written TRANSPOSED: Vt[bh][d][t] bf16. (R0 layout)
// ---------------------------------------------------------------------------
__global__ __launch_bounds__(256) void v_proj_t(
    const float* __restrict__ x,
    const float* __restrict__ Wv1, const float* __restrict__ Wv2,
    short* __restrict__ Vt)
{
    int bh = blockIdx.x >> 6;
    int tt = blockIdx.x & 63;
    int head = bh & 1, b = bh >> 1;
    int t  = tt * 64 + (threadIdx.x & 63);
    int dg = threadIdx.x >> 6;
    const float* Wv = head ? Wv2 : Wv1;
    const float* xp = x + (size_t)(b * T_SEQ + t) * 6 + head * 3;
    float x0 = xp[0], x1 = xp[1], x2 = xp[2];
    size_t base = (size_t)bh * 64 * T_SEQ + t;
    #pragma unroll
    for (int k = 0; k < 16; ++k) {
        int d = dg * 16 + k;
        float v = x0 * Wv[d] + x1 * Wv[64 + d] + x2 * Wv[128 + d];
        Vt[base + (size_t)d * T_SEQ] = f2bfs(v);
    }
}

// ---------------------------------------------------------------------------
// Kernel 3: causal flash attention, (tile, kv-half) wave split.
//   R6 rationale: R5(balanced) == R0(imbalanced) == 72.4us proves the wall is
//   NOT loop-length latency; it's per-CU under-coverage (2 waves/SIMD can't
//   hide lgkm/barrier stalls; VALUBusy 41%). This round cleanly raises TLP:
//   - Wave W owns ONE (tile, kv-half): tile = W>>1 (E=+0 / O=+32), half = W&1.
//     Per-wave state halves (acc 32, qf 16, one Sv) -> ~130 VGPR -> 3/SIMD
//     (launch_bounds(256,3)); per-wave dependency chain also halves.
//   - Chunk = 64 kv; LDS = dbuf x (K 8K + V 8K) = 32 KB -> LDS allows 5
//     blocks/CU; grid 1024 single-pair blocks -> 3 resident/CU + backfill,
//     12 waves/CU (1.5x R5).
//   - Block handles pair s (tiles 64s, 64s+32), n = s+1 chunks; LONG-FIRST
//     dispatch (s = 63 - rank) + 256-block backfill absorbs imbalance
//     (R5-vs-R0 proved imbalance is free under work-conserving behavior).
//   - K/V LDS layouts, swizzles, fragment reads, mask rule are EXACTLY R0's
//     verified forms (V LDS [64d][128B], swz=(ql&7)<<4). Combine = 1 round
//     (2 partials/tile: half1 publishes, half0 absorbs+writes).
// ---------------------------------------------------------------------------
__global__ __launch_bounds__(256, 3) void attn(
    const short* __restrict__ Q, const short* __restrict__ K,
    const short* __restrict__ Vt, float* __restrict__ Hf)
{
    __shared__ __align__(16) char smem[32768];  // dbuf 2 x (K 8K + V 8K)

    int id = blockIdx.x;                 // 1024
    int xcd = id & 7, r = id >> 3;       // r 0..127
    int bh = xcd * 2 + (r & 1);          // 2 bh per XCD (L2 locality)
    int s  = 63 - (r >> 1);              // pair index, LONGEST FIRST
    int tid = threadIdx.x;
    int W = tid >> 6;
    int lane = tid & 63;
    int ql = lane & 31, h = lane >> 5;
    int tile = W >> 1, half = W & 1;     // wave's (tile, kv-half)
    int t0 = 64 * s + 32 * tile;
    int q  = t0 + ql;
    int n  = s + 1;                      // 64-kv chunks
    int head = bh & 1, bb = bh >> 1;

    size_t kvbase = (size_t)bh * (T_SEQ * 64);

    // Q fragment (B-operand): lane holds Q[q][ks*16 + h*8 + j]
    bf16x8 qf[4];
    #pragma unroll
    for (int ks = 0; ks < 4; ++ks)
        qf[ks] = *(const bf16x8*)(Q + kvbase + (size_t)q * 64 + ks * 16 + h * 8);

    // staging maps (256 threads): row = tid>>3 (0..31), slot = tid&7,
    // pre-swizzled source column; LDS dest linear (swizzle applied on read).
    int krl = tid >> 3;
    int kcol = ((tid & 7) ^ (krl & 7)) * 8;
    const short* ksrc0 = K + kvbase + kcol;              // + srow*64
    const short* vsrc0 = Vt + kvbase + kcol;             // + d*T_SEQ + kv

    f32x16 acc0, acc1;
    #pragma unroll
    for (int rr = 0; rr < 16; ++rr) { acc0[rr] = 0.f; acc1[rr] = 0.f; }
    float l = 0.f;
    int swz = (ql & 7) << 4;

#define STAGE(bsel, kvv)                                                        \
    {                                                                           \
        char* kb = smem + (bsel) * 16384;                                       \
        char* vb = kb + 8192;                                                   \
        _Pragma("unroll")                                                       \
        for (int z = 0; z < 2; ++z) {                                           \
            int srow = (kvv) + 32 * z + krl;                                    \
            srow = srow > (T_SEQ - 1) ? (T_SEQ - 1) : srow;                     \
            __builtin_amdgcn_global_load_lds(                                   \
                (gptr_t)(ksrc0 + (size_t)srow * 64),                            \
                (lptr_t)(kb + z * 4096 + tid * 16), 16, 0, 0);                  \
        }                                                                       \
        int vkv = (kvv) > (T_SEQ - 64) ? (T_SEQ - 64) : (kvv);                  \
        _Pragma("unroll")                                                       \
        for (int z = 0; z < 2; ++z)                                             \
            __builtin_amdgcn_global_load_lds(                                   \
                (gptr_t)(vsrc0 + (size_t)(32 * z + krl) * T_SEQ + vkv),         \
                (lptr_t)(vb + z * 4096 + tid * 16), 16, 0, 0);                  \
    }

#define QK_SM(pf0, pf1)                                                         \
        {                                                                       \
            f32x16 Sv;                                                          \
            _Pragma("unroll") for (int rr = 0; rr < 16; ++rr) Sv[rr] = 0.f;     \
            Sv = __builtin_amdgcn_mfma_f32_32x32x16_bf16(kf0, qf[0], Sv,0,0,0); \
            Sv = __builtin_amdgcn_mfma_f32_32x32x16_bf16(kf1, qf[1], Sv,0,0,0); \
            Sv = __builtin_amdgcn_mfma_f32_32x32x16_bf16(kf2, qf[2], Sv,0,0,0); \
            Sv = __builtin_amdgcn_mfma_f32_32x32x16_bf16(kf3, qf[3], Sv,0,0,0); \
            bool needmask = (kv0 + 32 * half + 31 > t0);  /* max_kv > t0 */     \
            uint32_t pw[8];                                                     \
            float l0 = 0.f, l1 = 0.f;                                           \
            _Pragma("unroll") for (int e = 0; e < 8; ++e) {                     \
                float p0 = __builtin_amdgcn_exp2f(Sv[2 * e]);                   \
                float p1 = __builtin_amdgcn_exp2f(Sv[2 * e + 1]);               \
                if (needmask) {                                                 \
                    int kv = kv0 + 32 * half + 4 * h + 2 * (e & 1) + 8 * (e >> 1); \
                    p0 = (kv     <= q) ? p0 : 0.f;                              \
                    p1 = (kv + 1 <= q) ? p1 : 0.f;                              \
                }                                                               \
                l0 += p0; l1 += p1;                                             \
                pw[e] = cvtpk(p0, p1);                                          \
            }                                                                   \
            l += l0 + l1;                                                       \
            {                                                                   \
                uint32_t a0 = pw[0], b0 = pw[2], a1 = pw[1], b1 = pw[3];        \
                asm("v_permlane32_swap_b32 %0, %1" : "+v"(a0), "+v"(b0));       \
                asm("v_permlane32_swap_b32 %0, %1" : "+v"(a1), "+v"(b1));       \
                u32x4 fr = {a0, a1, b0, b1};                                    \
                pf0 = __builtin_bit_cast(bf16x8, fr);                           \
                uint32_t c0 = pw[4], d0 = pw[6], c1 = pw[5], d1 = pw[7];        \
                asm("v_permlane32_swap_b32 %0, %1" : "+v"(c0), "+v"(d0));       \
                asm("v_permlane32_swap_b32 %0, %1" : "+v"(c1), "+v"(d1));       \
                u32x4 fr1 = {c0, c1, d0, d1};                                   \
                pf1 = __builtin_bit_cast(bf16x8, fr1);                          \
            }                                                                   \
        }

#define BODY(cc)                                                                \
    {                                                                           \
        const int kv0 = 64 * (cc);                                              \
        if ((cc) + 1 < n) STAGE(((cc) + 1) & 1, kv0 + 64);                      \
        const char* kb = smem + ((cc) & 1) * 16384;                             \
        const char* vb = kb + 8192;                                             \
        const char* krw = kb + (32 * half + ql) * 128;                          \
        bf16x8 kf0 = *(const bf16x8*)(krw + ((0 * 32 + h * 16) ^ swz));         \
        bf16x8 kf1 = *(const bf16x8*)(krw + ((1 * 32 + h * 16) ^ swz));         \
        bf16x8 kf2 = *(const bf16x8*)(krw + ((2 * 32 + h * 16) ^ swz));         \
        bf16x8 kf3 = *(const bf16x8*)(krw + ((3 * 32 + h * 16) ^ swz));         \
        bool act = (kv0 + 32 * half <= t0 + 31);                                \
        bf16x8 pf0, pf1;                                                        \
        __builtin_amdgcn_s_setprio(1);                                          \
        if (act) QK_SM(pf0, pf1)                                                \
        const char* vr0 = vb + ql * 128;                                        \
        const char* vr1 = vb + (32 + ql) * 128;                                 \
        int vc0 = (64 * half + 16 * h) ^ swz;                                   \
        int vc1 = (64 * half + 32 + 16 * h) ^ swz;                              \
        bf16x8 vf00 = *(const bf16x8*)(vr0 + vc0);                              \
        bf16x8 vf01 = *(const bf16x8*)(vr0 + vc1);                              \
        bf16x8 vf10 = *(const bf16x8*)(vr1 + vc0);                              \
        bf16x8 vf11 = *(const bf16x8*)(vr1 + vc1);                              \
        if (act) {                                                              \
            acc0 = __builtin_amdgcn_mfma_f32_32x32x16_bf16(vf00, pf0, acc0, 0, 0, 0); \
            acc0 = __builtin_amdgcn_mfma_f32_32x32x16_bf16(vf01, pf1, acc0, 0, 0, 0); \
            acc1 = __builtin_amdgcn_mfma_f32_32x32x16_bf16(vf10, pf0, acc1, 0, 0, 0); \
            acc1 = __builtin_amdgcn_mfma_f32_32x32x16_bf16(vf11, pf1, acc1, 0, 0, 0); \
        }                                                                       \
        __builtin_amdgcn_s_setprio(0);                                          \
        __syncthreads();                                                        \
    }

    STAGE(0, 0);                         // prologue: chunk 0 -> buf 0
    __syncthreads();

    for (int c = 0; c < n; ++c) BODY(c);
#undef BODY
#undef QK_SM
#undef STAGE

    // ---- combine: 2 partials/tile. half1 publishes, half0 absorbs+writes.
    l += __shfl_xor(l, 32);
    float* sg = (float*)smem + tile * 2112 + lane * 33;  // 2 x [64][33] f32
    if (half == 1) {
        #pragma unroll
        for (int g = 0; g < 4; ++g) {
            *(f32x4*)(sg + 4 * g)      = f32x4{acc0[4*g+0], acc0[4*g+1], acc0[4*g+2], acc0[4*g+3]};
            *(f32x4*)(sg + 16 + 4 * g) = f32x4{acc1[4*g+0], acc1[4*g+1], acc1[4*g+2], acc1[4*g+3]};
        }
        sg[32] = l;
    }
    __syncthreads();
    if (half == 0) {
        #pragma unroll
        for (int g = 0; g < 4; ++g) {
            f32x4 u0 = *(f32x4*)(sg + 4 * g);
            f32x4 u1 = *(f32x4*)(sg + 16 + 4 * g);
            acc0[4*g+0] += u0[0]; acc0[4*g+1] += u0[1]; acc0[4*g+2] += u0[2]; acc0[4*g+3] += u0[3];
            acc1[4*g+0] += u1[0]; acc1[4*g+1] += u1[1]; acc1[4*g+2] += u1[2]; acc1[4*g+3] += u1[3];
        }
        l += sg[32];
        float rl = 1.0f / l;
        float* hp = Hf + ((size_t)(bb * T_SEQ) + t0 + ql) * 128 + head * 64 + 4 * h;
        #pragma unroll
        for (int g2 = 0; g2 < 4; ++g2) {
            f32x4 s0 = { acc0[g2*4+0]*rl, acc0[g2*4+1]*rl, acc0[g2*4+2]*rl, acc0[g2*4+3]*rl };
            *(f32x4*)(hp + 8 * g2) = s0;               // d = 8*g2+4h+0..3
            f32x4 s1 = { acc1[g2*4+0]*rl, acc1[g2*4+1]*rl, acc1[g2*4+2]*rl, acc1[g2*4+3]*rl };
            *(f32x4*)(hp + 32 + 8 * g2) = s1;          // d = 32+8*g2+4h+0..3
        }
    }
}

// ---------------------------------------------------------------------------
// Kernel 4a: one-shot Wout -> Wt bf16, transposed + xor-swizzled for LDS.
// ---------------------------------------------------------------------------
__global__ __launch_bounds__(256) void prep_wt(
    const float* __restrict__ Wout, short* __restrict__ Wt)
{
    int tid = blockIdx.x * 256 + threadIdx.x;   // 16384
    int j = tid >> 7, k = tid & 127;
    float v = Wout[k * 128 + j];
    int slot = k >> 3;
    Wt[j * 128 + (((slot ^ (j & 7)) << 3) | (k & 7))] = f2bfs(v);
}

// ---------------------------------------------------------------------------
// Kernel 4b: out = H(32768x128 f32, in d_out) @ Wout -> f32 (in place).
// Row-block-diagonal: each wave reads only its own 16 rows before writing.
// ---------------------------------------------------------------------------
__global__ __launch_bounds__(256) void out_proj(
    const float* Hf, const short* __restrict__ Wt, float* out)
{
    __shared__ __align__(16) char lws[32768];
    int tid = threadIdx.x;
    int w = tid >> 6, lane = tid & 63, c = lane & 15, g = lane >> 4;
    int cs = c & 7;
    #pragma unroll
    for (int z = 0; z < 8; ++z)
        __builtin_amdgcn_global_load_lds((gptr_t)(Wt + z * 2048 + w * 512 + lane * 8),
                                         (lptr_t)(lws + z * 4096 + w * 1024), 16, 0, 0);
    __syncthreads();

    int row0 = blockIdx.x * 64 + w * 16;
    bf16x8 af[4];
    const float* hp = Hf + (size_t)(row0 + c) * 128 + g * 8;
    #pragma unroll
    for (int kc = 0; kc < 4; ++kc) {
        f32x4 x0 = *(const f32x4*)(hp + kc * 32);
        f32x4 x1 = *(const f32x4*)(hp + kc * 32 + 4);
        u32x4 wv = { cvtpk(x0[0], x0[1]), cvtpk(x0[2], x0[3]),
                     cvtpk(x1[0], x1[1]), cvtpk(x1[2], x1[3]) };
        af[kc] = __builtin_bit_cast(bf16x8, wv);
    }
    #pragma unroll
    for (int jt = 0; jt < 8; ++jt) {
        f32x4 accum = {0.f, 0.f, 0.f, 0.f};
        #pragma unroll
        for (int kc = 0; kc < 4; ++kc) {
            int row = jt * 16 + c;
            bf16x8 bfr = *(const bf16x8*)(lws + row * 256 + (((kc * 4 + g) ^ cs) << 4));
            accum = __builtin_amdgcn_mfma_f32_16x16x32_bf16(af[kc], bfr, accum, 0, 0, 0);
        }
        #pragma unroll
        for (int r = 0; r < 4; ++r)
            out[(size_t)(row0 + g * 4 + r) * 128 + jt * 16 + c] = accum[r];
    }
}

// ---------------------------------------------------------------------------
extern "C" void kernel_launch(void* const* d_in, const int* in_sizes, int n_in,
                              void* d_out, int out_size, void* d_ws, size_t ws_size,
                              hipStream_t stream)
{
    (void)in_sizes; (void)n_in; (void)out_size; (void)ws_size;
    const float* x    = (const float*)d_in[0];
    const float* Wq1  = (const float*)d_in[1];
    const float* Wk1  = (const float*)d_in[2];
    const float* Wv1  = (const float*)d_in[3];
    const float* Wq2  = (const float*)d_in[4];
    const float* Wk2  = (const float*)d_in[5];
    const float* Wv2  = (const float*)d_in[6];
    const float* Wout = (const float*)d_in[7];
    float* out = (float*)d_out;

    char* ws = (char*)d_ws;
    short* Q  = (short*)(ws);                               // 8 MiB (dead after attn)
    short* K  = (short*)(ws + (size_t)8  * 1024 * 1024);    // 8 MiB
    short* Vt = (short*)(ws + (size_t)16 * 1024 * 1024);    // 8 MiB
    short* Wt = Q;                                          // reuse Q region
    float* Hf = out;                                        // f32 H lives in d_out

    qk_proj <<<8192, 256, 0, stream>>>(x, Wq1, Wk1, Wq2, Wk2, Q, K);
    v_proj_t<<<1024, 256, 0, stream>>>(x, Wv1, Wv2, Vt);
    attn    <<<1024, 256, 0, stream>>>(Q, K, Vt, Hf);
    prep_wt <<<  64, 256, 0, stream>>>(Wout, Wt);
    out_proj<<< 512, 256, 0, stream>>>(Hf, Wt, out);
}

// Round 7
// 96.516 us; speedup vs baseline: 1.7227x; 1.0012x over previous
//
#include <hip/hip_runtime.h>
#include <hip/hip_bf16.h>
#include <stdint.h>

#define T_SEQ 4096

typedef float  f32x4   __attribute__((ext_vector_type(4)));
typedef float  f32x16  __attribute__((ext_vector_type(16)));
typedef short  bf16x8  __attribute__((ext_vector_type(8)));
typedef unsigned int u32x4 __attribute__((ext_vector_type(4)));

typedef const __attribute__((address_space(1))) uint32_t* gptr_t;
typedef __attribute__((address_space(3))) uint32_t* lptr_t;

__device__ __forceinline__ uint32_t f2bf1(float f) {
    uint32_t u = __float_as_uint(f);
    return (u + 0x7fffu + ((u >> 16) & 1u)) >> 16;   // RNE f32->bf16
}
__device__ __forceinline__ short f2bfs(float f) { return (short)f2bf1(f); }
__device__ __forceinline__ uint32_t cvtpk(float lo, float hi) {
    uint32_t r;
    asm("v_cvt_pk_bf16_f32 %0, %1, %2" : "=v"(r) : "v"(lo), "v"(hi));
    return r;
}

// ---------------------------------------------------------------------------
// Kernel 1: Q,K projections. Q pre-scaled by 0.125*log2(e) (softmax uses 2^x).
// Layout: [bh=b*2+h][t][64] bf16.
// ---------------------------------------------------------------------------
__global__ __launch_bounds__(256) void qk_proj(
    const float* __restrict__ x,
    const float* __restrict__ Wq1, const float* __restrict__ Wk1,
    const float* __restrict__ Wq2, const float* __restrict__ Wk2,
    short* __restrict__ Q, short* __restrict__ K)
{
    int idx = blockIdx.x * 256 + threadIdx.x;
    int d = idx & 63;
    int t = (idx >> 6) & (T_SEQ - 1);
    int b = idx >> 18;
    const float* xp = x + (size_t)(b * T_SEQ + t) * 6;
    float x0 = xp[0], x1 = xp[1], x2 = xp[2];
    float x3 = xp[3], x4 = xp[4], x5 = xp[5];
    const float QS = 0.125f * 1.44269504088896340736f;
    float q1 = (x0 * Wq1[d] + x1 * Wq1[64 + d] + x2 * Wq1[128 + d]) * QS;
    float k1 =  x0 * Wk1[d] + x1 * Wk1[64 + d] + x2 * Wk1[128 + d];
    float q2 = (x3 * Wq2[d] + x4 * Wq2[64 + d] + x5 * Wq2[128 + d]) * QS;
    float k2 =  x3 * Wk2[d] + x4 * Wk2[64 + d] + x5 * Wk2[128 + d];
    size_t base1 = ((size_t)(b * 2 + 0) * T_SEQ + t) * 64 + d;
    size_t base2 = ((size_t)(b * 2 + 1) * T_SEQ + t) * 64 + d;
    Q[base1] = f2bfs(q1);  Q[base2] = f2bfs(q2);
    K[base1] = f2bfs(k1);  K[base2] = f2bfs(k2);
}

// ---------------------------------------------------------------------------
// Kernel 2: V projection written TRANSPOSED: Vt[bh][d][t] bf16. (R0 layout)
// ---------------------------------------------------------------------------
__global__ __launch_bounds__(256) void v_proj_t(
    const float* __restrict__ x,
    const float* __restrict__ Wv1, const float* __restrict__ Wv2,
    short* __restrict__ Vt)
{
    int bh = blockIdx.x >> 6;
    int tt = blockIdx.x & 63;
    int head = bh & 1, b = bh >> 1;
    int t  = tt * 64 + (threadIdx.x & 63);
    int dg = threadIdx.x >> 6;
    const float* Wv = head ? Wv2 : Wv1;
    const float* xp = x + (size_t)(b * T_SEQ + t) * 6 + head * 3;
    float x0 = xp[0], x1 = xp[1], x2 = xp[2];
    size_t base = (size_t)bh * 64 * T_SEQ + t;
    #pragma unroll
    for (int k = 0; k < 16; ++k) {
        int d = dg * 16 + k;
        float v = x0 * Wv[d] + x1 * Wv[64 + d] + x2 * Wv[128 + d];
        Vt[base + (size_t)d * T_SEQ] = f2bfs(v);
    }
}

// ---------------------------------------------------------------------------
// Kernel 3: causal flash attention, (tile, kv-half) wave split.
//   R7: single change vs R6 -- __launch_bounds__(256, 4) so all 4 grid
//   blocks/CU are CO-RESIDENT (R6's (256,3) capped residency at 3 blocks).
//   Rationale from R0==R5==R6==72.4us invariance: kernel is per-wave
//   critical-path latency-bound (duty ~26%); same-block waves are phase-
//   correlated by the per-chunk barrier, so extra waves only help if they
//   come from INDEPENDENT blocks. 4 blocks/CU puts 4 independent barrier
//   domains on each SIMD (each block's 4 waves spread 1/SIMD).
//   Budget check: LDS 32KB x 4 = 128KB <= 160 OK; unified regs 52 VGPR +
//   32 AGPR = 84 <= 128 OK (no spill expected; WRITE_SIZE is the canary).
//   Dispatch order gives each CU a mix of block lengths (~{63,47,31,15})
//   -> per-CU total work near-uniform; long-first order keeps tail small.
// ---------------------------------------------------------------------------
__global__ __launch_bounds__(256, 4) void attn(
    const short* __restrict__ Q, const short* __restrict__ K,
    const short* __restrict__ Vt, float* __restrict__ Hf)
{
    __shared__ __align__(16) char smem[32768];  // dbuf 2 x (K 8K + V 8K)

    int id = blockIdx.x;                 // 1024
    int xcd = id & 7, r = id >> 3;       // r 0..127
    int bh = xcd * 2 + (r & 1);          // 2 bh per XCD (L2 locality)
    int s  = 63 - (r >> 1);              // pair index, LONGEST FIRST
    int tid = threadIdx.x;
    int W = tid >> 6;
    int lane = tid & 63;
    int ql = lane & 31, h = lane >> 5;
    int tile = W >> 1, half = W & 1;     // wave's (tile, kv-half)
    int t0 = 64 * s + 32 * tile;
    int q  = t0 + ql;
    int n  = s + 1;                      // 64-kv chunks
    int head = bh & 1, bb = bh >> 1;

    size_t kvbase = (size_t)bh * (T_SEQ * 64);

    // Q fragment (B-operand): lane holds Q[q][ks*16 + h*8 + j]
    bf16x8 qf[4];
    #pragma unroll
    for (int ks = 0; ks < 4; ++ks)
        qf[ks] = *(const bf16x8*)(Q + kvbase + (size_t)q * 64 + ks * 16 + h * 8);

    // staging maps (256 threads): row = tid>>3 (0..31), slot = tid&7,
    // pre-swizzled source column; LDS dest linear (swizzle applied on read).
    int krl = tid >> 3;
    int kcol = ((tid & 7) ^ (krl & 7)) * 8;
    const short* ksrc0 = K + kvbase + kcol;              // + srow*64
    const short* vsrc0 = Vt + kvbase + kcol;             // + d*T_SEQ + kv

    f32x16 acc0, acc1;
    #pragma unroll
    for (int rr = 0; rr < 16; ++rr) { acc0[rr] = 0.f; acc1[rr] = 0.f; }
    float l = 0.f;
    int swz = (ql & 7) << 4;

#define STAGE(bsel, kvv)                                                        \
    {                                                                           \
        char* kb = smem + (bsel) * 16384;                                       \
        char* vb = kb + 8192;                                                   \
        _Pragma("unroll")                                                       \
        for (int z = 0; z < 2; ++z) {                                           \
            int srow = (kvv) + 32 * z + krl;                                    \
            srow = srow > (T_SEQ - 1) ? (T_SEQ - 1) : srow;                     \
            __builtin_amdgcn_global_load_lds(                                   \
                (gptr_t)(ksrc0 + (size_t)srow * 64),                            \
                (lptr_t)(kb + z * 4096 + tid * 16), 16, 0, 0);                  \
        }                                                                       \
        int vkv = (kvv) > (T_SEQ - 64) ? (T_SEQ - 64) : (kvv);                  \
        _Pragma("unroll")                                                       \
        for (int z = 0; z < 2; ++z)                                             \
            __builtin_amdgcn_global_load_lds(                                   \
                (gptr_t)(vsrc0 + (size_t)(32 * z + krl) * T_SEQ + vkv),         \
                (lptr_t)(vb + z * 4096 + tid * 16), 16, 0, 0);                  \
    }

#define QK_SM(pf0, pf1)                                                         \
        {                                                                       \
            f32x16 Sv;                                                          \
            _Pragma("unroll") for (int rr = 0; rr < 16; ++rr) Sv[rr] = 0.f;     \
            Sv = __builtin_amdgcn_mfma_f32_32x32x16_bf16(kf0, qf[0], Sv,0,0,0); \
            Sv = __builtin_amdgcn_mfma_f32_32x32x16_bf16(kf1, qf[1], Sv,0,0,0); \
            Sv = __builtin_amdgcn_mfma_f32_32x32x16_bf16(kf2, qf[2], Sv,0,0,0); \
            Sv = __builtin_amdgcn_mfma_f32_32x32x16_bf16(kf3, qf[3], Sv,0,0,0); \
            bool needmask = (kv0 + 32 * half + 31 > t0);  /* max_kv > t0 */     \
            uint32_t pw[8];                                                     \
            float l0 = 0.f, l1 = 0.f;                                           \
            _Pragma("unroll") for (int e = 0; e < 8; ++e) {                     \
                float p0 = __builtin_amdgcn_exp2f(Sv[2 * e]);                   \
                float p1 = __builtin_amdgcn_exp2f(Sv[2 * e + 1]);               \
                if (needmask) {                                                 \
                    int kv = kv0 + 32 * half + 4 * h + 2 * (e & 1) + 8 * (e >> 1); \
                    p0 = (kv     <= q) ? p0 : 0.f;                              \
                    p1 = (kv + 1 <= q) ? p1 : 0.f;                              \
                }                                                               \
                l0 += p0; l1 += p1;                                             \
                pw[e] = cvtpk(p0, p1);                                          \
            }                                                                   \
            l += l0 + l1;                                                       \
            {                                                                   \
                uint32_t a0 = pw[0], b0 = pw[2], a1 = pw[1], b1 = pw[3];        \
                asm("v_permlane32_swap_b32 %0, %1" : "+v"(a0), "+v"(b0));       \
                asm("v_permlane32_swap_b32 %0, %1" : "+v"(a1), "+v"(b1));       \
                u32x4 fr = {a0, a1, b0, b1};                                    \
                pf0 = __builtin_bit_cast(bf16x8, fr);                           \
                uint32_t c0 = pw[4], d0 = pw[6], c1 = pw[5], d1 = pw[7];        \
                asm("v_permlane32_swap_b32 %0, %1" : "+v"(c0), "+v"(d0));       \
                asm("v_permlane32_swap_b32 %0, %1" : "+v"(c1), "+v"(d1));       \
                u32x4 fr1 = {c0, c1, d0, d1};                                   \
                pf1 = __builtin_bit_cast(bf16x8, fr1);                          \
            }                                                                   \
        }

#define BODY(cc)                                                                \
    {                                                                           \
        const int kv0 = 64 * (cc);                                              \
        if ((cc) + 1 < n) STAGE(((cc) + 1) & 1, kv0 + 64);                      \
        const char* kb = smem + ((cc) & 1) * 16384;                             \
        const char* vb = kb + 8192;                                             \
        const char* krw = kb + (32 * half + ql) * 128;                          \
        bf16x8 kf0 = *(const bf16x8*)(krw + ((0 * 32 + h * 16) ^ swz));         \
        bf16x8 kf1 = *(const bf16x8*)(krw + ((1 * 32 + h * 16) ^ swz));         \
        bf16x8 kf2 = *(const bf16x8*)(krw + ((2 * 32 + h * 16) ^ swz));         \
        bf16x8 kf3 = *(const bf16x8*)(krw + ((3 * 32 + h * 16) ^ swz));         \
        bool act = (kv0 + 32 * half <= t0 + 31);                                \
        bf16x8 pf0, pf1;                                                        \
        __builtin_amdgcn_s_setprio(1);                                          \
        if (act) QK_SM(pf0, pf1)                                                \
        const char* vr0 = vb + ql * 128;                                        \
        const char* vr1 = vb + (32 + ql) * 128;                                 \
        int vc0 = (64 * half + 16 * h) ^ swz;                                   \
        int vc1 = (64 * half + 32 + 16 * h) ^ swz;                              \
        bf16x8 vf00 = *(const bf16x8*)(vr0 + vc0);                              \
        bf16x8 vf01 = *(const bf16x8*)(vr0 + vc1);                              \
        bf16x8 vf10 = *(const bf16x8*)(vr1 + vc0);                              \
        bf16x8 vf11 = *(const bf16x8*)(vr1 + vc1);                              \
        if (act) {                                                              \
            acc0 = __builtin_amdgcn_mfma_f32_32x32x16_bf16(vf00, pf0, acc0, 0, 0, 0); \
            acc0 = __builtin_amdgcn_mfma_f32_32x32x16_bf16(vf01, pf1, acc0, 0, 0, 0); \
            acc1 = __builtin_amdgcn_mfma_f32_32x32x16_bf16(vf10, pf0, acc1, 0, 0, 0); \
            acc1 = __builtin_amdgcn_mfma_f32_32x32x16_bf16(vf11, pf1, acc1, 0, 0, 0); \
        }                                                                       \
        __builtin_amdgcn_s_setprio(0);                                          \
        __syncthreads();                                                        \
    }

    STAGE(0, 0);                         // prologue: chunk 0 -> buf 0
    __syncthreads();

    for (int c = 0; c < n; ++c) BODY(c);
#undef BODY
#undef QK_SM
#undef STAGE

    // ---- combine: 2 partials/tile. half1 publishes, half0 absorbs+writes.
    l += __shfl_xor(l, 32);
    float* sg = (float*)smem + tile * 2112 + lane * 33;  // 2 x [64][33] f32
    if (half == 1) {
        #pragma unroll
        for (int g = 0; g < 4; ++g) {
            *(f32x4*)(sg + 4 * g)      = f32x4{acc0[4*g+0], acc0[4*g+1], acc0[4*g+2], acc0[4*g+3]};
            *(f32x4*)(sg + 16 + 4 * g) = f32x4{acc1[4*g+0], acc1[4*g+1], acc1[4*g+2], acc1[4*g+3]};
        }
        sg[32] = l;
    }
    __syncthreads();
    if (half == 0) {
        #pragma unroll
        for (int g = 0; g < 4; ++g) {
            f32x4 u0 = *(f32x4*)(sg + 4 * g);
            f32x4 u1 = *(f32x4*)(sg + 16 + 4 * g);
            acc0[4*g+0] += u0[0]; acc0[4*g+1] += u0[1]; acc0[4*g+2] += u0[2]; acc0[4*g+3] += u0[3];
            acc1[4*g+0] += u1[0]; acc1[4*g+1] += u1[1]; acc1[4*g+2] += u1[2]; acc1[4*g+3] += u1[3];
        }
        l += sg[32];
        float rl = 1.0f / l;
        float* hp = Hf + ((size_t)(bb * T_SEQ) + t0 + ql) * 128 + head * 64 + 4 * h;
        #pragma unroll
        for (int g2 = 0; g2 < 4; ++g2) {
            f32x4 s0 = { acc0[g2*4+0]*rl, acc0[g2*4+1]*rl, acc0[g2*4+2]*rl, acc0[g2*4+3]*rl };
            *(f32x4*)(hp + 8 * g2) = s0;               // d = 8*g2+4h+0..3
            f32x4 s1 = { acc1[g2*4+0]*rl, acc1[g2*4+1]*rl, acc1[g2*4+2]*rl, acc1[g2*4+3]*rl };
            *(f32x4*)(hp + 32 + 8 * g2) = s1;          // d = 32+8*g2+4h+0..3
        }
    }
}

// ---------------------------------------------------------------------------
// Kernel 4a: one-shot Wout -> Wt bf16, transposed + xor-swizzled for LDS.
// ---------------------------------------------------------------------------
__global__ __launch_bounds__(256) void prep_wt(
    const float* __restrict__ Wout, short* __restrict__ Wt)
{
    int tid = blockIdx.x * 256 + threadIdx.x;   // 16384
    int j = tid >> 7, k = tid & 127;
    float v = Wout[k * 128 + j];
    int slot = k >> 3;
    Wt[j * 128 + (((slot ^ (j & 7)) << 3) | (k & 7))] = f2bfs(v);
}

// ---------------------------------------------------------------------------
// Kernel 4b: out = H(32768x128 f32, in d_out) @ Wout -> f32 (in place).
// Row-block-diagonal: each wave reads only its own 16 rows before writing.
// ---------------------------------------------------------------------------
__global__ __launch_bounds__(256) void out_proj(
    const float* Hf, const short* __restrict__ Wt, float* out)
{
    __shared__ __align__(16) char lws[32768];
    int tid = threadIdx.x;
    int w = tid >> 6, lane = tid & 63, c = lane & 15, g = lane >> 4;
    int cs = c & 7;
    #pragma unroll
    for (int z = 0; z < 8; ++z)
        __builtin_amdgcn_global_load_lds((gptr_t)(Wt + z * 2048 + w * 512 + lane * 8),
                                         (lptr_t)(lws + z * 4096 + w * 1024), 16, 0, 0);
    __syncthreads();

    int row0 = blockIdx.x * 64 + w * 16;
    bf16x8 af[4];
    const float* hp = Hf + (size_t)(row0 + c) * 128 + g * 8;
    #pragma unroll
    for (int kc = 0; kc < 4; ++kc) {
        f32x4 x0 = *(const f32x4*)(hp + kc * 32);
        f32x4 x1 = *(const f32x4*)(hp + kc * 32 + 4);
        u32x4 wv = { cvtpk(x0[0], x0[1]), cvtpk(x0[2], x0[3]),
                     cvtpk(x1[0], x1[1]), cvtpk(x1[2], x1[3]) };
        af[kc] = __builtin_bit_cast(bf16x8, wv);
    }
    #pragma unroll
    for (int jt = 0; jt < 8; ++jt) {
        f32x4 accum = {0.f, 0.f, 0.f, 0.f};
        #pragma unroll
        for (int kc = 0; kc < 4; ++kc) {
            int row = jt * 16 + c;
            bf16x8 bfr = *(const bf16x8*)(lws + row * 256 + (((kc * 4 + g) ^ cs) << 4));
            accum = __builtin_amdgcn_mfma_f32_16x16x32_bf16(af[kc], bfr, accum, 0, 0, 0);
        }
        #pragma unroll
        for (int r = 0; r < 4; ++r)
            out[(size_t)(row0 + g * 4 + r) * 128 + jt * 16 + c] = accum[r];
    }
}

// ---------------------------------------------------------------------------
extern "C" void kernel_launch(void* const* d_in, const int* in_sizes, int n_in,
                              void* d_out, int out_size, void* d_ws, size_t ws_size,
                              hipStream_t stream)
{
    (void)in_sizes; (void)n_in; (void)out_size; (void)ws_size;
    const float* x    = (const float*)d_in[0];
    const float* Wq1  = (const float*)d_in[1];
    const float* Wk1  = (const float*)d_in[2];
    const float* Wv1  = (const float*)d_in[3];
    const float* Wq2  = (const float*)d_in[4];
    const float* Wk2  = (const float*)d_in[5];
    const float* Wv2  = (const float*)d_in[6];
    const float* Wout = (const float*)d_in[7];
    float* out = (float*)d_out;

    char* ws = (char*)d_ws;
    short* Q  = (short*)(ws);                               // 8 MiB (dead after attn)
    short* K  = (short*)(ws + (size_t)8  * 1024 * 1024);    // 8 MiB
    short* Vt = (short*)(ws + (size_t)16 * 1024 * 1024);    // 8 MiB
    short* Wt = Q;                                          // reuse Q region
    float* Hf = out;                                        // f32 H lives in d_out

    qk_proj <<<8192, 256, 0, stream>>>(x, Wq1, Wk1, Wq2, Wk2, Q, K);
    v_proj_t<<<1024, 256, 0, stream>>>(x, Wv1, Wv2, Vt);
    attn    <<<1024, 256, 0, stream>>>(Q, K, Vt, Hf);
    prep_wt <<<  64, 256, 0, stream>>>(Wout, Wt);
    out_proj<<< 512, 256, 0, stream>>>(Hf, Wt, out);
}

// Round 8
// 89.084 us; speedup vs baseline: 1.8664x; 1.0834x over previous
//
#include <hip/hip_runtime.h>
#include <hip/hip_bf16.h>
#include <stdint.h>

#define T_SEQ 4096

typedef float  f32x4   __attribute__((ext_vector_type(4)));
typedef float  f32x16  __attribute__((ext_vector_type(16)));
typedef short  bf16x8  __attribute__((ext_vector_type(8)));
typedef unsigned int u32x4 __attribute__((ext_vector_type(4)));

typedef const __attribute__((address_space(1))) uint32_t* gptr_t;
typedef __attribute__((address_space(3))) uint32_t* lptr_t;

__device__ __forceinline__ uint32_t f2bf1(float f) {
    uint32_t u = __float_as_uint(f);
    return (u + 0x7fffu + ((u >> 16) & 1u)) >> 16;   // RNE f32->bf16
}
__device__ __forceinline__ short f2bfs(float f) { return (short)f2bf1(f); }
__device__ __forceinline__ uint32_t cvtpk(float lo, float hi) {
    uint32_t r;
    asm("v_cvt_pk_bf16_f32 %0, %1, %2" : "=v"(r) : "v"(lo), "v"(hi));
    return r;
}

// ---------------------------------------------------------------------------
// Kernel 1: Q,K projections. Q pre-scaled by 0.125*log2(e) (softmax uses 2^x).
// Layout: [bh=b*2+h][t][64] bf16.
// ---------------------------------------------------------------------------
__global__ __launch_bounds__(256) void qk_proj(
    const float* __restrict__ x,
    const float* __restrict__ Wq1, const float* __restrict__ Wk1,
    const float* __restrict__ Wq2, const float* __restrict__ Wk2,
    short* __restrict__ Q, short* __restrict__ K)
{
    int idx = blockIdx.x * 256 + threadIdx.x;
    int d = idx & 63;
    int t = (idx >> 6) & (T_SEQ - 1);
    int b = idx >> 18;
    const float* xp = x + (size_t)(b * T_SEQ + t) * 6;
    float x0 = xp[0], x1 = xp[1], x2 = xp[2];
    float x3 = xp[3], x4 = xp[4], x5 = xp[5];
    const float QS = 0.125f * 1.44269504088896340736f;
    float q1 = (x0 * Wq1[d] + x1 * Wq1[64 + d] + x2 * Wq1[128 + d]) * QS;
    float k1 =  x0 * Wk1[d] + x1 * Wk1[64 + d] + x2 * Wk1[128 + d];
    float q2 = (x3 * Wq2[d] + x4 * Wq2[64 + d] + x5 * Wq2[128 + d]) * QS;
    float k2 =  x3 * Wk2[d] + x4 * Wk2[64 + d] + x5 * Wk2[128 + d];
    size_t base1 = ((size_t)(b * 2 + 0) * T_SEQ + t) * 64 + d;
    size_t base2 = ((size_t)(b * 2 + 1) * T_SEQ + t) * 64 + d;
    Q[base1] = f2bfs(q1);  Q[base2] = f2bfs(q2);
    K[base1] = f2bfs(k1);  K[base2] = f2bfs(k2);
}

// ---------------------------------------------------------------------------
// Kernel 2: V projection written TRANSPOSED: Vt[bh][d][t] bf16. (R0 layout)
// ---------------------------------------------------------------------------
__global__ __launch_bounds__(256) void v_proj_t(
    const float* __restrict__ x,
    const float* __restrict__ Wv1, const float* __restrict__ Wv2,
    short* __restrict__ Vt)
{
    int bh = blockIdx.x >> 6;
    int tt = blockIdx.x & 63;
    int head = bh & 1, b = bh >> 1;
    int t  = tt * 64 + (threadIdx.x & 63);
    int dg = threadIdx.x >> 6;
    const float* Wv = head ? Wv2 : Wv1;
    const float* xp = x + (size_t)(b * T_SEQ + t) * 6 + head * 3;
    float x0 = xp[0], x1 = xp[1], x2 = xp[2];
    size_t base = (size_t)bh * 64 * T_SEQ + t;
    #pragma unroll
    for (int k = 0; k < 16; ++k) {
        int d = dg * 16 + k;
        float v = x0 * Wv[d] + x1 * Wv[64 + d] + x2 * Wv[128 + d];
        Vt[base + (size_t)d * T_SEQ] = f2bfs(v);
    }
}

// ---------------------------------------------------------------------------
// Kernel 3: causal flash attention, (tile, kv-half) waves + KV-SPLIT blocks.
//   R8: model from R0==R5==R6==R7==72.4us: wall = (critical block's 32x32-
//   slice count == 64) x (~1.13us/slice, invariant under occupancy/conflict/
//   balance changes). So halve the FIRST factor: flash-decoding split.
//   Block (s, p): pair s (tiles 64s, 64s+32), processes chunks c = p, p+2,
//   ... < s+1 (chunk parity split) -> every block <= 32 bodies. Static-max
//   softmax => partials additive: block emits UNNORMALIZED acc and l.
//   p=0 -> Hf (d_out) + L0; p=1 -> P1 (ws) + L1. out_proj combines.
//   Body/mask/staging identical to R6 (chunk stride 2; dbuf by body parity;
//   no clamps needed -- all staged addresses provably in-range).
//   Degenerate blocks (p=1, s=0: 0 bodies) write zero partials; L0>0 always.
// ---------------------------------------------------------------------------
__global__ __launch_bounds__(256, 4) void attn(
    const short* __restrict__ Q, const short* __restrict__ K,
    const short* __restrict__ Vt, float* __restrict__ Hf,
    float* __restrict__ P1, float* __restrict__ L0, float* __restrict__ L1)
{
    __shared__ __align__(16) char smem[32768];  // dbuf 2 x (K 8K + V 8K)

    int id = blockIdx.x;                 // 2048
    int xcd = id & 7, rest = id >> 3;    // rest 0..255
    int bh = xcd * 2 + (rest & 1);       // 2 bh per XCD (L2 locality)
    int rem = rest >> 1;                 // 0..127
    int s  = 63 - (rem >> 1);            // pair index, LONGEST FIRST
    int p  = rem & 1;                    // kv-parity half
    int tid = threadIdx.x;
    int W = tid >> 6;
    int lane = tid & 63;
    int ql = lane & 31, h = lane >> 5;
    int tile = W >> 1, half = W & 1;     // wave's (tile, kv-half)
    int t0 = 64 * s + 32 * tile;
    int q  = t0 + ql;
    int n  = s + 1;                      // total 64-kv chunks for this pair
    int nb = (n - p + 1) >> 1;           // my chunk count: ceil((n-p)/2)

    size_t kvbase = (size_t)bh * (T_SEQ * 64);

    // Q fragment (B-operand): lane holds Q[q][ks*16 + h*8 + j]
    bf16x8 qf[4];
    #pragma unroll
    for (int ks = 0; ks < 4; ++ks)
        qf[ks] = *(const bf16x8*)(Q + kvbase + (size_t)q * 64 + ks * 16 + h * 8);

    // staging maps (256 threads): row = tid>>3 (0..31), slot = tid&7,
    // pre-swizzled source column; LDS dest linear (swizzle applied on read).
    int krl = tid >> 3;
    int kcol = ((tid & 7) ^ (krl & 7)) * 8;
    const short* ksrc0 = K + kvbase + kcol;              // + srow*64
    const short* vsrc0 = Vt + kvbase + kcol;             // + d*T_SEQ + kv

    f32x16 acc0, acc1;
    #pragma unroll
    for (int rr = 0; rr < 16; ++rr) { acc0[rr] = 0.f; acc1[rr] = 0.f; }
    float l = 0.f;
    int swz = (ql & 7) << 4;

#define STAGE(bsel, kvv)                                                        \
    {                                                                           \
        char* kb = smem + (bsel) * 16384;                                       \
        char* vb = kb + 8192;                                                   \
        _Pragma("unroll")                                                       \
        for (int z = 0; z < 2; ++z)                                             \
            __builtin_amdgcn_global_load_lds(                                   \
                (gptr_t)(ksrc0 + (size_t)((kvv) + 32 * z + krl) * 64),          \
                (lptr_t)(kb + z * 4096 + tid * 16), 16, 0, 0);                  \
        _Pragma("unroll")                                                       \
        for (int z = 0; z < 2; ++z)                                             \
            __builtin_amdgcn_global_load_lds(                                   \
                (gptr_t)(vsrc0 + (size_t)(32 * z + krl) * T_SEQ + (kvv)),       \
                (lptr_t)(vb + z * 4096 + tid * 16), 16, 0, 0);                  \
    }

#define QK_SM(pf0, pf1)                                                         \
        {                                                                       \
            f32x16 Sv;                                                          \
            _Pragma("unroll") for (int rr = 0; rr < 16; ++rr) Sv[rr] = 0.f;     \
            Sv = __builtin_amdgcn_mfma_f32_32x32x16_bf16(kf0, qf[0], Sv,0,0,0); \
            Sv = __builtin_amdgcn_mfma_f32_32x32x16_bf16(kf1, qf[1], Sv,0,0,0); \
            Sv = __builtin_amdgcn_mfma_f32_32x32x16_bf16(kf2, qf[2], Sv,0,0,0); \
            Sv = __builtin_amdgcn_mfma_f32_32x32x16_bf16(kf3, qf[3], Sv,0,0,0); \
            bool needmask = (kv0 + 32 * half + 31 > t0);  /* max_kv > t0 */     \
            uint32_t pw[8];                                                     \
            float l0 = 0.f, l1 = 0.f;                                           \
            _Pragma("unroll") for (int e = 0; e < 8; ++e) {                     \
                float p0 = __builtin_amdgcn_exp2f(Sv[2 * e]);                   \
                float p1 = __builtin_amdgcn_exp2f(Sv[2 * e + 1]);               \
                if (needmask) {                                                 \
                    int kv = kv0 + 32 * half + 4 * h + 2 * (e & 1) + 8 * (e >> 1); \
                    p0 = (kv     <= q) ? p0 : 0.f;                              \
                    p1 = (kv + 1 <= q) ? p1 : 0.f;                              \
                }                                                               \
                l0 += p0; l1 += p1;                                             \
                pw[e] = cvtpk(p0, p1);                                          \
            }                                                                   \
            l += l0 + l1;                                                       \
            {                                                                   \
                uint32_t a0 = pw[0], b0 = pw[2], a1 = pw[1], b1 = pw[3];        \
                asm("v_permlane32_swap_b32 %0, %1" : "+v"(a0), "+v"(b0));       \
                asm("v_permlane32_swap_b32 %0, %1" : "+v"(a1), "+v"(b1));       \
                u32x4 fr = {a0, a1, b0, b1};                                    \
                pf0 = __builtin_bit_cast(bf16x8, fr);                           \
                uint32_t c0 = pw[4], d0 = pw[6], c1 = pw[5], d1 = pw[7];        \
                asm("v_permlane32_swap_b32 %0, %1" : "+v"(c0), "+v"(d0));       \
                asm("v_permlane32_swap_b32 %0, %1" : "+v"(c1), "+v"(d1));       \
                u32x4 fr1 = {c0, c1, d0, d1};                                   \
                pf1 = __builtin_bit_cast(bf16x8, fr1);                          \
            }                                                                   \
        }

#define BODY(jj)                                                                \
    {                                                                           \
        const int kv0 = 64 * (p + 2 * (jj));                                    \
        if ((jj) + 1 < nb) STAGE(((jj) + 1) & 1, kv0 + 128);                    \
        const char* kb = smem + ((jj) & 1) * 16384;                             \
        const char* vb = kb + 8192;                                             \
        const char* krw = kb + (32 * half + ql) * 128;                          \
        bf16x8 kf0 = *(const bf16x8*)(krw + ((0 * 32 + h * 16) ^ swz));         \
        bf16x8 kf1 = *(const bf16x8*)(krw + ((1 * 32 + h * 16) ^ swz));         \
        bf16x8 kf2 = *(const bf16x8*)(krw + ((2 * 32 + h * 16) ^ swz));         \
        bf16x8 kf3 = *(const bf16x8*)(krw + ((3 * 32 + h * 16) ^ swz));         \
        bool act = (kv0 + 32 * half <= t0 + 31);                                \
        bf16x8 pf0, pf1;                                                        \
        __builtin_amdgcn_s_setprio(1);                                          \
        if (act) QK_SM(pf0, pf1)                                                \
        const char* vr0 = vb + ql * 128;                                        \
        const char* vr1 = vb + (32 + ql) * 128;                                 \
        int vc0 = (64 * half + 16 * h) ^ swz;                                   \
        int vc1 = (64 * half + 32 + 16 * h) ^ swz;                              \
        bf16x8 vf00 = *(const bf16x8*)(vr0 + vc0);                              \
        bf16x8 vf01 = *(const bf16x8*)(vr0 + vc1);                              \
        bf16x8 vf10 = *(const bf16x8*)(vr1 + vc0);                              \
        bf16x8 vf11 = *(const bf16x8*)(vr1 + vc1);                              \
        if (act) {                                                              \
            acc0 = __builtin_amdgcn_mfma_f32_32x32x16_bf16(vf00, pf0, acc0, 0, 0, 0); \
            acc0 = __builtin_amdgcn_mfma_f32_32x32x16_bf16(vf01, pf1, acc0, 0, 0, 0); \
            acc1 = __builtin_amdgcn_mfma_f32_32x32x16_bf16(vf10, pf0, acc1, 0, 0, 0); \
            acc1 = __builtin_amdgcn_mfma_f32_32x32x16_bf16(vf11, pf1, acc1, 0, 0, 0); \
        }                                                                       \
        __builtin_amdgcn_s_setprio(0);                                          \
        __syncthreads();                                                        \
    }

    if (nb > 0) STAGE(0, 64 * p);        // prologue: first chunk -> buf 0
    __syncthreads();

    for (int j = 0; j < nb; ++j) BODY(j);
#undef BODY
#undef QK_SM
#undef STAGE

    // ---- combine: 2 partials/tile. half1 publishes, half0 absorbs+writes
    //      UNNORMALIZED partial (acc, l) to this parity's buffers.
    l += __shfl_xor(l, 32);
    float* sg = (float*)smem + tile * 2112 + lane * 33;  // 2 x [64][33] f32
    if (half == 1) {
        #pragma unroll
        for (int g = 0; g < 4; ++g) {
            *(f32x4*)(sg + 4 * g)      = f32x4{acc0[4*g+0], acc0[4*g+1], acc0[4*g+2], acc0[4*g+3]};
            *(f32x4*)(sg + 16 + 4 * g) = f32x4{acc1[4*g+0], acc1[4*g+1], acc1[4*g+2], acc1[4*g+3]};
        }
        sg[32] = l;
    }
    __syncthreads();
    if (half == 0) {
        #pragma unroll
        for (int g = 0; g < 4; ++g) {
            f32x4 u0 = *(f32x4*)(sg + 4 * g);
            f32x4 u1 = *(f32x4*)(sg + 16 + 4 * g);
            acc0[4*g+0] += u0[0]; acc0[4*g+1] += u0[1]; acc0[4*g+2] += u0[2]; acc0[4*g+3] += u0[3];
            acc1[4*g+0] += u1[0]; acc1[4*g+1] += u1[1]; acc1[4*g+2] += u1[2]; acc1[4*g+3] += u1[3];
        }
        l += sg[32];
        int head = bh & 1, bb = bh >> 1;
        float* Pdst = p ? P1 : Hf;
        float* Ldst = p ? L1 : L0;
        float* hp = Pdst + ((size_t)(bb * T_SEQ) + t0 + ql) * 128 + head * 64 + 4 * h;
        #pragma unroll
        for (int g2 = 0; g2 < 4; ++g2) {
            f32x4 s0 = { acc0[g2*4+0], acc0[g2*4+1], acc0[g2*4+2], acc0[g2*4+3] };
            *(f32x4*)(hp + 8 * g2) = s0;               // d = 8*g2+4h+0..3
            f32x4 s1 = { acc1[g2*4+0], acc1[g2*4+1], acc1[g2*4+2], acc1[g2*4+3] };
            *(f32x4*)(hp + 32 + 8 * g2) = s1;          // d = 32+8*g2+4h+0..3
        }
        if (h == 0)                       // one lane per q-row
            Ldst[(size_t)bh * T_SEQ + t0 + ql] = l;
    }
}

// ---------------------------------------------------------------------------
// Kernel 4a: one-shot Wout -> Wt bf16, transposed + xor-swizzled for LDS.
// ---------------------------------------------------------------------------
__global__ __launch_bounds__(256) void prep_wt(
    const float* __restrict__ Wout, short* __restrict__ Wt)
{
    int tid = blockIdx.x * 256 + threadIdx.x;   // 16384
    int j = tid >> 7, k = tid & 127;
    float v = Wout[k * 128 + j];
    int slot = k >> 3;
    Wt[j * 128 + (((slot ^ (j & 7)) << 3) | (k & 7))] = f2bfs(v);
}

// ---------------------------------------------------------------------------
// Kernel 4b: out = ((P0+P1) * 1/(L0+L1)) @ Wout -> f32 (in place over P0).
// Row-block-diagonal: each wave reads only its own 16 rows before writing.
// Normalization folded into the bf16 fragment build (per-head rl).
// ---------------------------------------------------------------------------
__global__ __launch_bounds__(256) void out_proj(
    const float* P0, const float* __restrict__ P1,
    const float* __restrict__ L0, const float* __restrict__ L1,
    const short* __restrict__ Wt, float* out)
{
    __shared__ __align__(16) char lws[32768];
    int tid = threadIdx.x;
    int w = tid >> 6, lane = tid & 63, c = lane & 15, g = lane >> 4;
    int cs = c & 7;
    #pragma unroll
    for (int z = 0; z < 8; ++z)
        __builtin_amdgcn_global_load_lds((gptr_t)(Wt + z * 2048 + w * 512 + lane * 8),
                                         (lptr_t)(lws + z * 4096 + w * 1024), 16, 0, 0);
    __syncthreads();

    int row0 = blockIdx.x * 64 + w * 16;
    int r = row0 + c;
    int b = r >> 12, t = r & (T_SEQ - 1);
    float rl0 = 1.0f / (L0[(size_t)(b * 2 + 0) * T_SEQ + t] + L1[(size_t)(b * 2 + 0) * T_SEQ + t]);
    float rl1 = 1.0f / (L0[(size_t)(b * 2 + 1) * T_SEQ + t] + L1[(size_t)(b * 2 + 1) * T_SEQ + t]);

    bf16x8 af[4];
    const float* hp0 = P0 + (size_t)r * 128 + g * 8;
    const float* hp1 = P1 + (size_t)r * 128 + g * 8;
    #pragma unroll
    for (int kc = 0; kc < 4; ++kc) {
        float rl = (kc < 2) ? rl0 : rl1;          // d = kc*32+g*8+.. ; head = d>>6
        f32x4 x0 = *(const f32x4*)(hp0 + kc * 32);
        f32x4 x1 = *(const f32x4*)(hp0 + kc * 32 + 4);
        f32x4 y0 = *(const f32x4*)(hp1 + kc * 32);
        f32x4 y1 = *(const f32x4*)(hp1 + kc * 32 + 4);
        u32x4 wv = { cvtpk((x0[0]+y0[0])*rl, (x0[1]+y0[1])*rl),
                     cvtpk((x0[2]+y0[2])*rl, (x0[3]+y0[3])*rl),
                     cvtpk((x1[0]+y1[0])*rl, (x1[1]+y1[1])*rl),
                     cvtpk((x1[2]+y1[2])*rl, (x1[3]+y1[3])*rl) };
        af[kc] = __builtin_bit_cast(bf16x8, wv);
    }
    #pragma unroll
    for (int jt = 0; jt < 8; ++jt) {
        f32x4 accum = {0.f, 0.f, 0.f, 0.f};
        #pragma unroll
        for (int kc = 0; kc < 4; ++kc) {
            int row = jt * 16 + c;
            bf16x8 bfr = *(const bf16x8*)(lws + row * 256 + (((kc * 4 + g) ^ cs) << 4));
            accum = __builtin_amdgcn_mfma_f32_16x16x32_bf16(af[kc], bfr, accum, 0, 0, 0);
        }
        #pragma unroll
        for (int rr = 0; rr < 4; ++rr)
            out[(size_t)(row0 + g * 4 + rr) * 128 + jt * 16 + c] = accum[rr];
    }
}

// ---------------------------------------------------------------------------
extern "C" void kernel_launch(void* const* d_in, const int* in_sizes, int n_in,
                              void* d_out, int out_size, void* d_ws, size_t ws_size,
                              hipStream_t stream)
{
    (void)in_sizes; (void)n_in; (void)out_size; (void)ws_size;
    const float* x    = (const float*)d_in[0];
    const float* Wq1  = (const float*)d_in[1];
    const float* Wk1  = (const float*)d_in[2];
    const float* Wv1  = (const float*)d_in[3];
    const float* Wq2  = (const float*)d_in[4];
    const float* Wk2  = (const float*)d_in[5];
    const float* Wv2  = (const float*)d_in[6];
    const float* Wout = (const float*)d_in[7];
    float* out = (float*)d_out;

    char* ws = (char*)d_ws;
    short* Q  = (short*)(ws);                               // 8 MiB (dead after attn)
    short* K  = (short*)(ws + (size_t)8  * 1024 * 1024);    // 8 MiB
    short* Vt = (short*)(ws + (size_t)16 * 1024 * 1024);    // 8 MiB
    float* P1 = (float*)(ws + (size_t)24 * 1024 * 1024);    // 16 MiB partial
    float* L0 = (float*)(ws + (size_t)40 * 1024 * 1024);    // 256 KiB
    float* L1 = (float*)(ws + (size_t)40 * 1024 * 1024 + 262144);
    short* Wt = Q;                                          // reuse Q region
    float* Hf = out;                                        // P0 lives in d_out

    qk_proj <<<8192, 256, 0, stream>>>(x, Wq1, Wk1, Wq2, Wk2, Q, K);
    v_proj_t<<<1024, 256, 0, stream>>>(x, Wv1, Wv2, Vt);
    attn    <<<2048, 256, 0, stream>>>(Q, K, Vt, Hf, P1, L0, L1);
    prep_wt <<<  64, 256, 0, stream>>>(Wout, Wt);
    out_proj<<< 512, 256, 0, stream>>>(Hf, P1, L0, L1, Wt, out);
}